// Round 2
// baseline (1771760.352 us; speedup 1.0000x reference)
//
#include <hip/hip_runtime.h>
#include <math.h>

#define BSZ 2048   // batch steps
#define MM  256    // memory slots
#define EE  128    // embedding dim
#define HSS 512    // summarizer hidden
#define HPP 256    // processor hidden
#define NWG 128
#define TPB 256

// workspace offsets (in floats); first 64 floats = barrier state (memset to 0)
#define OFF_PE   64
#define OFF_R0   (OFF_PE + MM*EE)
#define OFF_W0   (OFF_R0 + BSZ)
#define OFF_MP   (OFF_W0 + BSZ*MM)        // memPE double buffer: 2*MM*EE
#define OFF_SW   (OFF_MP + 2*MM*EE)       // writer scores rows 2..257, dbuf: 2*MM*MM
#define OFF_EV   (OFF_SW + 2*MM*MM)       // per-WG exp-weighted partials: NWG*EE
#define OFF_ES   (OFF_EV + NWG*EE)        // per-WG exp sums: NWG
#define OFF_MS2  (OFF_ES + NWG)           // ms2: EE
#define OFF_SW1  (OFF_MS2 + EE)           // writer row-1 scores: MM
#define OFF_CS   (OFF_SW1 + MM)           // composed Wemb@Ws[0:128,:]: 4*HSS
#define OFF_CBS  (OFF_CS + 4*HSS)         // bemb@Ws[0:128,:]: HSS
#define OFF_CP   (OFF_CBS + HSS)          // composed Wemb@Wp1[0:128,:]: 4*HPP
#define OFF_CBP  (OFF_CP + 4*HPP)         // bemb@Wp1[0:128,:]: HPP
// total ≈ 776512 floats ≈ 3.0 MB

struct KParams {
  const float *state, *mem0, *Wemb, *bemb, *Wr1, *br1, *Wr2, *br2;
  const float *Ww1, *bw1, *Ww2, *bw2, *Ws, *bs, *Wa, *ba, *Wc, *bc;
  const float *Wp1, *bp1, *Wp2, *bp2;
  float *out;
  float *ws;
};

// ---- software grid barrier (sense via monotonically increasing generation) ----
__device__ __forceinline__ void gridBarrier(unsigned* bar, int tid) {
  __syncthreads();
  if (tid == 0) {
    __threadfence();
    unsigned gen = __hip_atomic_load(&bar[1], __ATOMIC_RELAXED, __HIP_MEMORY_SCOPE_AGENT);
    unsigned arrived = __hip_atomic_fetch_add(&bar[0], 1u, __ATOMIC_ACQ_REL, __HIP_MEMORY_SCOPE_AGENT);
    if (arrived == NWG - 1) {
      __hip_atomic_store(&bar[0], 0u, __ATOMIC_RELAXED, __HIP_MEMORY_SCOPE_AGENT);
      __hip_atomic_store(&bar[1], gen + 1u, __ATOMIC_RELEASE, __HIP_MEMORY_SCOPE_AGENT);
    } else {
      while (__hip_atomic_load(&bar[1], __ATOMIC_ACQUIRE, __HIP_MEMORY_SCOPE_AGENT) == gen) {
        __builtin_amdgcn_s_sleep(2);
      }
    }
    __threadfence();
  }
  __syncthreads();
}

__device__ __forceinline__ float blockReduceSum(float v, float* sRed, int tid) {
  for (int o = 32; o > 0; o >>= 1) v += __shfl_down(v, o, 64);
  __syncthreads();
  if ((tid & 63) == 0) sRed[tid >> 6] = v;
  __syncthreads();
  return sRed[0] + sRed[1] + sRed[2] + sRed[3];
}

// A (reader scores -> exp partials) + C (writer score rows) for this WG's 2 rows.
// Both rows done in ONE pass over Wr1/Ww1/Ww2.
__device__ __forceinline__ void stageAC(
    int g, int tid, int c0, const KParams& p,
    float (*sX)[EE], float (*sH2)[HSS], float* sRed,
    float* swdst, float* evecg, float* esumg)
{
  const int h0 = tid, h1 = tid + TPB;
  // ---- A: reader hidden (both rows) + scores
  float A00=0.f,A01=0.f,A10=0.f,A11=0.f;   // [half][row]
  for (int e = 0; e < EE; e += 2) {
    const float* w = p.Wr1 + (size_t)e*HSS;
    float x00=sX[0][e], x10=sX[1][e], x01=sX[0][e+1], x11=sX[1][e+1];
    float wa=w[h0], wb=w[h1], wc=w[HSS+h0], wd=w[HSS+h1];
    A00 += x00*wa; A01 += x10*wa;
    A10 += x00*wb; A11 += x10*wb;
    A00 += x01*wc; A01 += x11*wc;
    A10 += x01*wd; A11 += x11*wd;
  }
  float b0 = p.br1[h0], b1 = p.br1[h1], wr0 = p.Wr2[h0], wr1 = p.Wr2[h1];
  float hA0 = fmaxf(A00+b0, 0.f), hA1 = fmaxf(A01+b0, 0.f);
  float hB0 = fmaxf(A10+b1, 0.f), hB1 = fmaxf(A11+b1, 0.f);
  float sc0 = blockReduceSum(hA0*wr0 + hB0*wr1, sRed, tid) + p.br2[0];
  float sc1 = blockReduceSum(hA1*wr0 + hB1*wr1, sRed, tid) + p.br2[0];
  float es0 = expf(sc0), es1 = expf(sc1);
  if (tid < EE) evecg[(size_t)g*EE + tid] = es0*sX[0][tid] + es1*sX[1][tid];
  if (tid == 0) esumg[g] = es0 + es1;
  // ---- C: writer hidden (both rows)
  float C00=0.f,C01=0.f,C10=0.f,C11=0.f;
  for (int e = 0; e < EE; e += 2) {
    const float* w = p.Ww1 + (size_t)e*HSS;
    float x00=sX[0][e], x10=sX[1][e], x01=sX[0][e+1], x11=sX[1][e+1];
    float wa=w[h0], wb=w[h1], wc=w[HSS+h0], wd=w[HSS+h1];
    C00 += x00*wa; C01 += x10*wa;
    C10 += x00*wb; C11 += x10*wb;
    C00 += x01*wc; C01 += x11*wc;
    C10 += x01*wd; C11 += x11*wd;
  }
  float bw0 = p.bw1[h0], bw1v = p.bw1[h1];
  sH2[0][h0] = fmaxf(C00+bw0, 0.f);  sH2[1][h0] = fmaxf(C01+bw0, 0.f);
  sH2[0][h1] = fmaxf(C10+bw1v, 0.f); sH2[1][h1] = fmaxf(C11+bw1v, 0.f);
  __syncthreads();
  // ---- writer score rows (both rows, one Ww2 pass)
  {
    const int cc = tid;
    float q0=0.f, q1=0.f;
    for (int h = 0; h < HSS; h += 2) {
      float wa = p.Ww2[(size_t)h*MM+cc], wb = p.Ww2[(size_t)(h+1)*MM+cc];
      q0 += sH2[0][h]*wa + sH2[0][h+1]*wb;
      q1 += sH2[1][h]*wa + sH2[1][h+1]*wb;
    }
    float bb = p.bw2[cc];
    swdst[(size_t)c0*MM + cc]     = q0 + bb;
    swdst[(size_t)(c0+1)*MM + cc] = q1 + bb;
  }
  __syncthreads();
}

// D: per-column softmax over 258 writer scores + weighted sum + renorm + add pe.
__device__ __forceinline__ void stageD(
    int g, int tid, int c0, int t, const KParams& p, float* ws,
    float (*sX)[EE], float* sRed, float (*sEv)[264])
{
  const float* w0  = ws + OFF_W0 + (size_t)t*MM;
  const float* sw1 = ws + OFF_SW1;
  const float* ms2 = ws + OFF_MS2;
  const float* swc = ws + OFF_SW + (size_t)(t&1)*MM*MM;
  const float* mpc = ws + OFF_MP + (size_t)(t&1)*MM*EE;
  float* mpn = ws + OFF_MP + (size_t)((t+1)&1)*MM*EE;

  for (int r = tid; r < MM+2; r += TPB) {
    float s0, s1;
    if (r == 0)      { s0 = w0[c0];  s1 = w0[c0+1]; }
    else if (r == 1) { s0 = sw1[c0]; s1 = sw1[c0+1]; }
    else             { s0 = swc[(size_t)(r-2)*MM+c0]; s1 = swc[(size_t)(r-2)*MM+c0+1]; }
    sEv[0][r] = expf(s0); sEv[1][r] = expf(s1);
  }
  __syncthreads();
  if (tid < 128) {
    float u0 = sEv[0][tid] + sEv[0][tid+128];
    float u1 = sEv[1][tid] + sEv[1][tid+128];
    if (tid < 2) { u0 += sEv[0][tid+256]; u1 += sEv[1][tid+256]; }
    sRed[tid] = u0; sRed[TPB+tid] = u1;
  }
  __syncthreads();
  for (int s = 64; s > 0; s >>= 1) {
    if (tid < s) { sRed[tid] += sRed[tid+s]; sRed[TPB+tid] += sRed[TPB+tid+s]; }
    __syncthreads();
  }
  float inv0 = 1.f / sRed[0], inv1 = 1.f / sRed[TPB];
  __syncthreads();
  const int e = tid & (EE-1), hf = tid >> 7;
  float a0a=0.f,a0b=0.f,a1a=0.f,a1b=0.f;
  if (hf == 0) {
    const float* st = p.state + (size_t)t*4;
    float xv0 = st[0]*p.Wemb[e] + st[1]*p.Wemb[EE+e]
              + st[2]*p.Wemb[2*EE+e] + st[3]*p.Wemb[3*EE+e] + p.bemb[e];
    float xv1 = ms2[e];
    a0a = sEv[0][0]*xv0 + sEv[0][1]*xv1;
    a1a = sEv[1][0]*xv0 + sEv[1][1]*xv1;
  }
  {
    const int rbase = 2 + hf*128;
    const float* mp = mpc + (size_t)(rbase-2)*EE + e;
    for (int r = 0; r < 128; r += 2) {
      float xv0 = mp[(size_t)r*EE];
      float xv1 = mp[(size_t)(r+1)*EE];
      a0a += sEv[0][rbase+r]   * xv0;
      a1a += sEv[1][rbase+r]   * xv0;
      a0b += sEv[0][rbase+r+1] * xv1;
      a1b += sEv[1][rbase+r+1] * xv1;
    }
  }
  sRed[tid]     = a0a + a0b;
  sRed[TPB+tid] = a1a + a1b;
  __syncthreads();
  if (tid < EE) {
    sX[0][tid] = (sRed[tid] + sRed[128+tid]) * inv0;
    sX[1][tid] = (sRed[TPB+tid] + sRed[TPB+128+tid]) * inv1;
  }
  __syncthreads();
  if (tid < 128) {
    sRed[tid]     = sX[0][tid];
    sRed[128+tid] = sX[0][tid];
    sRed[256+tid] = sX[1][tid];
    sRed[384+tid] = sX[1][tid];
  }
  __syncthreads();
  for (int s = 64; s > 0; s >>= 1) {
    if (tid < s) {
      sRed[tid]     = fminf(sRed[tid], sRed[tid+s]);
      sRed[128+tid] = fmaxf(sRed[128+tid], sRed[128+tid+s]);
      sRed[256+tid] = fminf(sRed[256+tid], sRed[256+tid+s]);
      sRed[384+tid] = fmaxf(sRed[384+tid], sRed[384+tid+s]);
    }
    __syncthreads();
  }
  float mn0 = sRed[0], mx0 = sRed[128], mn1 = sRed[256], mx1 = sRed[384];
  __syncthreads();
  if (tid < EE) {
    float v0 = (sX[0][tid] - mn0) / (mx0 - mn0);
    float v1 = (sX[1][tid] - mn1) / (mx1 - mn1);
    float x0 = v0 + ws[OFF_PE + (size_t)c0*EE + tid];
    float x1 = v1 + ws[OFF_PE + (size_t)(c0+1)*EE + tid];
    mpn[(size_t)c0*EE + tid] = x0;
    mpn[(size_t)(c0+1)*EE + tid] = x1;
    sX[0][tid] = x0; sX[1][tid] = x1;
  }
  __syncthreads();
}

// Serial chain on WG0: mem_state -> h -> probs/val -> ms2 -> writer row-1 scores
__device__ __forceinline__ void leaderB(
    int tid, int t, const KParams& p, float* ws,
    float* sRed, float* sMS, float* sSE, float* sP1, float* sSmall, float (*sH2)[HSS])
{
  const float* evec = ws + OFF_EV;
  const float* esum = ws + OFF_ES;
  const float* cs  = ws + OFF_CS;
  const float* csb = ws + OFF_CBS;
  const float* cp  = ws + OFF_CP;
  const float* cpb = ws + OFF_CBP;
  const float* st = p.state + (size_t)t*4;
  const float s0 = st[0], s1 = st[1], s2 = st[2], s3 = st[3];

  if (tid < EE) {
    sSE[tid] = s0*p.Wemb[tid] + s1*p.Wemb[EE+tid]
             + s2*p.Wemb[2*EE+tid] + s3*p.Wemb[3*EE+tid] + p.bemb[tid];
  }
  float er0 = expf(ws[OFF_R0 + t]);
  if (tid < EE) {
    float acc = er0 * sSE[tid];
    #pragma unroll 4
    for (int q = 0; q < NWG; ++q) acc += evec[(size_t)q*EE + tid];
    sMS[tid] = acc;
  } else if (tid == EE) {
    float d = er0;
    for (int q = 0; q < NWG; ++q) d += esum[q];
    sSmall[0] = 1.f / d;
  }
  __syncthreads();
  float invd = sSmall[0];
  if (tid < EE) sMS[tid] *= invd;
  __syncthreads();
  const int j0 = tid, j1 = tid + TPB;
  // trunk h = relu(sh0 + mem_state-half + bias)
  float a0=0.f,a1=0.f,a2=0.f,a3=0.f,b0=0.f,b1=0.f,b2=0.f,b3=0.f;
  for (int e = 0; e < EE; e += 4) {
    const float* w = p.Ws + (size_t)(EE+e)*HSS;
    float m0=sMS[e],m1=sMS[e+1],m2=sMS[e+2],m3=sMS[e+3];
    a0+=m0*w[j0];        b0+=m0*w[j1];
    a1+=m1*w[HSS+j0];    b1+=m1*w[HSS+j1];
    a2+=m2*w[2*HSS+j0];  b2+=m2*w[2*HSS+j1];
    a3+=m3*w[3*HSS+j0];  b3+=m3*w[3*HSS+j1];
  }
  float sh0a = s0*cs[j0] + s1*cs[HSS+j0] + s2*cs[2*HSS+j0] + s3*cs[3*HSS+j0] + csb[j0];
  float sh0b = s0*cs[j1] + s1*cs[HSS+j1] + s2*cs[2*HSS+j1] + s3*cs[3*HSS+j1] + csb[j1];
  float hv0 = fmaxf(sh0a + (a0+a1)+(a2+a3) + p.bs[j0], 0.f);
  float hv1 = fmaxf(sh0b + (b0+b1)+(b2+b3) + p.bs[j1], 0.f);
  float pa[6];
  #pragma unroll
  for (int aa = 0; aa < 5; ++aa) pa[aa] = hv0*p.Wa[(size_t)j0*5+aa] + hv1*p.Wa[(size_t)j1*5+aa];
  pa[5] = hv0*p.Wc[j0] + hv1*p.Wc[j1];
  #pragma unroll
  for (int aa = 0; aa < 6; ++aa) {
    float r = blockReduceSum(pa[aa], sRed, tid);
    if (tid == 0) sSmall[1+aa] = r;
  }
  __syncthreads();
  if (tid == 0) {
    float l0=sSmall[1]+p.ba[0], l1=sSmall[2]+p.ba[1], l2=sSmall[3]+p.ba[2];
    float l3=sSmall[4]+p.ba[3], l4=sSmall[5]+p.ba[4];
    float mx = fmaxf(fmaxf(fmaxf(l0,l1),fmaxf(l2,l3)), l4);
    float e0=expf(l0-mx),e1=expf(l1-mx),e2=expf(l2-mx),e3=expf(l3-mx),e4=expf(l4-mx);
    float is = 1.f/(e0+e1+e2+e3+e4);
    float p0=e0*is,p1=e1*is,p2=e2*is,p3=e3*is,p4=e4*is;
    p.out[(size_t)t*5+0]=p0; p.out[(size_t)t*5+1]=p1; p.out[(size_t)t*5+2]=p2;
    p.out[(size_t)t*5+3]=p3; p.out[(size_t)t*5+4]=p4;
    float val = sSmall[6] + p.bc[0];
    p.out[(size_t)BSZ*5 + t] = val;
    sSmall[1]=p0; sSmall[2]=p1; sSmall[3]=p2; sSmall[4]=p3; sSmall[5]=p4; sSmall[6]=val;
  }
  __syncthreads();
  // p1 = relu(pin @ Wp1 + bp1)
  {
    const int k = tid;
    float acc = s0*cp[k] + s1*cp[HPP+k] + s2*cp[2*HPP+k] + s3*cp[3*HPP+k] + cpb[k] + p.bp1[k];
    float q0=0.f,q1=0.f,q2=0.f,q3=0.f;
    for (int e = 0; e < EE; e += 4) {
      const float* w = p.Wp1 + (size_t)(EE+e)*HPP;
      q0 += sMS[e]  * w[k];
      q1 += sMS[e+1]* w[HPP+k];
      q2 += sMS[e+2]* w[2*HPP+k];
      q3 += sMS[e+3]* w[3*HPP+k];
    }
    acc += (q0+q1)+(q2+q3);
    #pragma unroll
    for (int aa = 0; aa < 5; ++aa) acc += sSmall[1+aa] * p.Wp1[(size_t)(2*EE+aa)*HPP + k];
    acc += sSmall[6] * p.Wp1[(size_t)(2*EE+5)*HPP + k];
    sP1[k] = fmaxf(acc, 0.f);
  }
  __syncthreads();
  // ms2 = p1 @ Wp2 + bp2
  if (tid < EE) {
    float q0=0.f,q1=0.f,q2=0.f,q3=0.f;
    for (int k = 0; k < HPP; k += 4) {
      q0 += sP1[k]  * p.Wp2[(size_t) k   *EE + tid];
      q1 += sP1[k+1]* p.Wp2[(size_t)(k+1)*EE + tid];
      q2 += sP1[k+2]* p.Wp2[(size_t)(k+2)*EE + tid];
      q3 += sP1[k+3]* p.Wp2[(size_t)(k+3)*EE + tid];
    }
    float m = (q0+q1)+(q2+q3) + p.bp2[tid];
    sMS[tid] = m;
    ws[OFF_MS2 + tid] = m;
  }
  __syncthreads();
  // writer row-1 hidden + scores from ms2
  {
    float c0a=0.f,c1a=0.f,c2a=0.f,c3a=0.f,d0=0.f,d1=0.f,d2=0.f,d3=0.f;
    for (int e = 0; e < EE; e += 4) {
      const float* w = p.Ww1 + (size_t)e*HSS;
      float m0=sMS[e],m1=sMS[e+1],m2=sMS[e+2],m3=sMS[e+3];
      c0a+=m0*w[j0];       d0+=m0*w[j1];
      c1a+=m1*w[HSS+j0];   d1+=m1*w[HSS+j1];
      c2a+=m2*w[2*HSS+j0]; d2+=m2*w[2*HSS+j1];
      c3a+=m3*w[3*HSS+j0]; d3+=m3*w[3*HSS+j1];
    }
    sH2[0][j0] = fmaxf((c0a+c1a)+(c2a+c3a) + p.bw1[j0], 0.f);
    sH2[0][j1] = fmaxf((d0+d1)+(d2+d3) + p.bw1[j1], 0.f);
  }
  __syncthreads();
  {
    const int cc = tid;
    float q0=0.f,q1=0.f,q2=0.f,q3=0.f;
    for (int h = 0; h < HSS; h += 4) {
      q0 += sH2[0][h]  * p.Ww2[(size_t) h   *MM+cc];
      q1 += sH2[0][h+1]* p.Ww2[(size_t)(h+1)*MM+cc];
      q2 += sH2[0][h+2]* p.Ww2[(size_t)(h+2)*MM+cc];
      q3 += sH2[0][h+3]* p.Ww2[(size_t)(h+3)*MM+cc];
    }
    ws[OFF_SW1 + cc] = (q0+q1)+(q2+q3) + p.bw2[cc];
  }
  __syncthreads();
}

__global__ __launch_bounds__(TPB)
void toyac_kernel(KParams p) {
  const int g = blockIdx.x;
  const int tid = threadIdx.x;
  const int c0 = 2*g;
  float* ws = p.ws;
  unsigned* bar = (unsigned*)p.ws;

  __shared__ float sX[2][EE];
  __shared__ float sH2[2][HSS];
  __shared__ float sRed[2*TPB];
  __shared__ float sEv[2][264];
  __shared__ float sMS[EE];
  __shared__ float sSE[EE];
  __shared__ float sP1[HPP];
  __shared__ float sSmall[16];

  // ---------------- P0a: pe + memPE[0] (own rows), composed matrices ----------------
  {
    const int e = tid & (EE-1);
    const int j = tid >> 7;
    const int c = c0 + j;
    double dv = exp(-(double)(2*(e>>1)) * log(10000.0) / 128.0);
    double arg = (double)c * dv;
    float pev = ((e & 1) == 0) ? (float)sin(arg) : (float)cos(arg);
    ws[OFF_PE + (size_t)c*EE + e] = pev;
    ws[OFF_MP + (size_t)c*EE + e] = p.mem0[(size_t)c*EE + e] + pev;
  }
  if (g == 1) {  // CS = Wemb @ Ws[0:128,:], CBS = bemb @ Ws[0:128,:]
    for (int j = tid; j < HSS; j += TPB) {
      float c0a=0.f,c1a=0.f,c2a=0.f,c3a=0.f,cb=0.f;
      for (int e = 0; e < EE; ++e) {
        float wv = p.Ws[(size_t)e*HSS + j];
        c0a += p.Wemb[e]      * wv;
        c1a += p.Wemb[EE+e]   * wv;
        c2a += p.Wemb[2*EE+e] * wv;
        c3a += p.Wemb[3*EE+e] * wv;
        cb  += p.bemb[e]      * wv;
      }
      ws[OFF_CS + j]         = c0a;
      ws[OFF_CS + HSS + j]   = c1a;
      ws[OFF_CS + 2*HSS + j] = c2a;
      ws[OFF_CS + 3*HSS + j] = c3a;
      ws[OFF_CBS + j]        = cb;
    }
  }
  if (g == 2) {  // CP = Wemb @ Wp1[0:128,:], CBP = bemb @ Wp1[0:128,:]
    for (int k = tid; k < HPP; k += TPB) {
      float c0a=0.f,c1a=0.f,c2a=0.f,c3a=0.f,cb=0.f;
      for (int e = 0; e < EE; ++e) {
        float wv = p.Wp1[(size_t)e*HPP + k];
        c0a += p.Wemb[e]      * wv;
        c1a += p.Wemb[EE+e]   * wv;
        c2a += p.Wemb[2*EE+e] * wv;
        c3a += p.Wemb[3*EE+e] * wv;
        cb  += p.bemb[e]      * wv;
      }
      ws[OFF_CP + k]         = c0a;
      ws[OFF_CP + HPP + k]   = c1a;
      ws[OFF_CP + 2*HPP + k] = c2a;
      ws[OFF_CP + 3*HPP + k] = c3a;
      ws[OFF_CBP + k]        = cb;
    }
  }

  // ---------------- P0b: per-step R0, W0 (input-only precompute) ----------------
  const int j0 = tid, j1 = tid + TPB;
  for (int t = g; t < BSZ; t += NWG) {
    __syncthreads();
    if (tid < EE) {
      const float* st = p.state + (size_t)t*4;
      sMS[tid] = st[0]*p.Wemb[tid] + st[1]*p.Wemb[EE+tid]
               + st[2]*p.Wemb[2*EE+tid] + st[3]*p.Wemb[3*EE+tid] + p.bemb[tid];
    }
    __syncthreads();
    { // r0 = reader score of row0
      float a0=0.f,a1=0.f,a2=0.f,a3=0.f,b0=0.f,b1=0.f,b2=0.f,b3=0.f;
      for (int e = 0; e < EE; e += 4) {
        const float* w = p.Wr1 + (size_t)e*HSS;
        float m0=sMS[e],m1=sMS[e+1],m2=sMS[e+2],m3=sMS[e+3];
        a0+=m0*w[j0];        b0+=m0*w[j1];
        a1+=m1*w[HSS+j0];    b1+=m1*w[HSS+j1];
        a2+=m2*w[2*HSS+j0];  b2+=m2*w[2*HSS+j1];
        a3+=m3*w[3*HSS+j0];  b3+=m3*w[3*HSS+j1];
      }
      float hr0 = fmaxf((a0+a1)+(a2+a3) + p.br1[j0], 0.f);
      float hr1 = fmaxf((b0+b1)+(b2+b3) + p.br1[j1], 0.f);
      float sc = blockReduceSum(hr0*p.Wr2[j0] + hr1*p.Wr2[j1], sRed, tid);
      if (tid == 0) ws[OFF_R0 + t] = sc + p.br2[0];
    }
    { // w0 = writer score row0 (full 256 columns)
      float a0=0.f,a1=0.f,a2=0.f,a3=0.f,b0=0.f,b1=0.f,b2=0.f,b3=0.f;
      for (int e = 0; e < EE; e += 4) {
        const float* w = p.Ww1 + (size_t)e*HSS;
        float m0=sMS[e],m1=sMS[e+1],m2=sMS[e+2],m3=sMS[e+3];
        a0+=m0*w[j0];        b0+=m0*w[j1];
        a1+=m1*w[HSS+j0];    b1+=m1*w[HSS+j1];
        a2+=m2*w[2*HSS+j0];  b2+=m2*w[2*HSS+j1];
        a3+=m3*w[3*HSS+j0];  b3+=m3*w[3*HSS+j1];
      }
      sH2[0][j0] = fmaxf((a0+a1)+(a2+a3) + p.bw1[j0], 0.f);
      sH2[0][j1] = fmaxf((b0+b1)+(b2+b3) + p.bw1[j1], 0.f);
      __syncthreads();
      const int cc = tid;
      float q0=0.f,q1=0.f,q2=0.f,q3=0.f;
      for (int h = 0; h < HSS; h += 4) {
        q0 += sH2[0][h]  * p.Ww2[(size_t) h   *MM+cc];
        q1 += sH2[0][h+1]* p.Ww2[(size_t)(h+1)*MM+cc];
        q2 += sH2[0][h+2]* p.Ww2[(size_t)(h+2)*MM+cc];
        q3 += sH2[0][h+3]* p.Ww2[(size_t)(h+3)*MM+cc];
      }
      ws[OFF_W0 + (size_t)t*MM + cc] = (q0+q1)+(q2+q3) + p.bw2[cc];
    }
  }
  // prologue: scores + reader partials for step 0 (from initial memory, own rows only)
  {
    __syncthreads();
    const int e = tid & (EE-1), j = tid >> 7;
    sX[j][e] = ws[OFF_MP + (size_t)(c0+j)*EE + e];
  }
  __syncthreads();
  stageAC(g, tid, c0, p, sX, sH2, sRed, ws + OFF_SW, ws + OFF_EV, ws + OFF_ES);
  gridBarrier(bar, tid);

  // ---------------- main sequential loop ----------------
  for (int t = 0; t < BSZ; ++t) {
    if (g == 0) leaderB(tid, t, p, ws, sRed, sMS, sSE, sP1, sSmall, sH2);
    gridBarrier(bar, tid);
    if (t < BSZ - 1) {
      stageD(g, tid, c0, t, p, ws, sX, sRed, sEv);
      stageAC(g, tid, c0, p, sX, sH2, sRed,
              ws + OFF_SW + (size_t)((t+1)&1)*MM*MM, ws + OFF_EV, ws + OFF_ES);
    }
    gridBarrier(bar, tid);
  }
}

extern "C" void kernel_launch(void* const* d_in, const int* in_sizes, int n_in,
                              void* d_out, int out_size, void* d_ws, size_t ws_size,
                              hipStream_t stream) {
  hipMemsetAsync(d_ws, 0, 256, stream);  // zero barrier state (stream-ordered, capture-safe)
  KParams kp;
  kp.state = (const float*)d_in[0];
  kp.mem0  = (const float*)d_in[1];
  kp.Wemb  = (const float*)d_in[2];
  kp.bemb  = (const float*)d_in[3];
  kp.Wr1   = (const float*)d_in[4];
  kp.br1   = (const float*)d_in[5];
  kp.Wr2   = (const float*)d_in[6];
  kp.br2   = (const float*)d_in[7];
  kp.Ww1   = (const float*)d_in[8];
  kp.bw1   = (const float*)d_in[9];
  kp.Ww2   = (const float*)d_in[10];
  kp.bw2   = (const float*)d_in[11];
  kp.Ws    = (const float*)d_in[12];
  kp.bs    = (const float*)d_in[13];
  kp.Wa    = (const float*)d_in[14];
  kp.ba    = (const float*)d_in[15];
  kp.Wc    = (const float*)d_in[16];
  kp.bc    = (const float*)d_in[17];
  kp.Wp1   = (const float*)d_in[18];
  kp.bp1   = (const float*)d_in[19];
  kp.Wp2   = (const float*)d_in[20];
  kp.bp2   = (const float*)d_in[21];
  kp.out   = (float*)d_out;
  kp.ws    = (float*)d_ws;
  toyac_kernel<<<dim3(NWG), dim3(TPB), 0, stream>>>(kp);
}

// Round 3
// 241374.512 us; speedup vs baseline: 7.3403x; 7.3403x over previous
//
#include <hip/hip_runtime.h>
#include <math.h>

#define BSZ 2048   // batch steps
#define MM  256    // memory slots
#define EE  128    // embedding dim
#define HSS 512    // summarizer hidden
#define HPP 256    // processor hidden
#define NWG 128    // worker blocks (2 memory rows each)
#define NWGT 129   // workers + 1 leader
#define LEADER 128
#define TPB 256

// workspace offsets (floats). First 512 floats: barrier flags/release (memset 0).
#define OFF_PE   512
#define OFF_R0   (OFF_PE + MM*EE)
#define OFF_W0   (OFF_R0 + BSZ)
#define OFF_MP   (OFF_W0 + BSZ*MM)        // memPE double buffer: 2*MM*EE
#define OFF_SW   (OFF_MP + 2*MM*EE)       // writer scores TRANSPOSED [buf][col][row]: 2*MM*MM
#define OFF_EV   (OFF_SW + 2*MM*MM)       // per-WG exp-weighted partials: NWG*EE
#define OFF_ES   (OFF_EV + NWG*EE)        // per-WG exp sums: NWG
#define OFF_MS2  (OFF_ES + NWG)           // ms2: EE
#define OFF_HMS  (OFF_MS2 + EE)           // relu(ms2@Ww1+bw1): HSS
#define OFF_CS   (OFF_HMS + HSS)          // Wemb@Ws[0:128,:]: 4*HSS (leader-local)
#define OFF_CBS  (OFF_CS + 4*HSS)         // bemb@Ws[0:128,:]: HSS
#define OFF_CP   (OFF_CBS + HSS)          // Wemb@Wp1[0:128,:]: 4*HPP
#define OFF_CBP  (OFF_CP + 4*HPP)         // bemb@Wp1[0:128,:]: HPP
// end ~777216 floats ~3.0 MB

struct KParams {
  const float *state, *mem0, *Wemb, *bemb, *Wr1, *br1, *Wr2, *br2;
  const float *Ww1, *bw1, *Ww2, *bw2, *Ws, *bs, *Wa, *ba, *Wc, *bc;
  const float *Wp1, *bp1, *Wp2, *bp2;
  float *out;
  float *ws;
};

// ---- relaxed agent-scope ops: coherent across XCDs, NO cache-wide maintenance ----
__device__ __forceinline__ float ldA(const float* p) {
  return __hip_atomic_load(p, __ATOMIC_RELAXED, __HIP_MEMORY_SCOPE_AGENT);
}
__device__ __forceinline__ void stA(float* p, float v) {
  __hip_atomic_store(p, v, __ATOMIC_RELAXED, __HIP_MEMORY_SCOPE_AGENT);
}
__device__ __forceinline__ unsigned ldAu(const unsigned* p) {
  return __hip_atomic_load(p, __ATOMIC_RELAXED, __HIP_MEMORY_SCOPE_AGENT);
}
__device__ __forceinline__ void stAu(unsigned* p, unsigned v) {
  __hip_atomic_store(p, v, __ATOMIC_RELAXED, __HIP_MEMORY_SCOPE_AGENT);
}

// flag-tree grid barrier: workers write own slot, leader scans in parallel, releases.
// Relaxed atomics only; HW ordering via vmcnt drain + s_barrier.
__device__ __forceinline__ void wsBarrier(unsigned* bar, int g, int tid, unsigned bgen) {
  asm volatile("s_waitcnt vmcnt(0)" ::: "memory");
  __syncthreads();
  if (g == LEADER) {
    if (tid < NWG) {
      while (ldAu(&bar[tid]) < bgen) __builtin_amdgcn_s_sleep(4);
    }
    __syncthreads();
    if (tid == 0) stAu(&bar[132], bgen);
  } else {
    if (tid == 0) {
      stAu(&bar[g], bgen);
      while (ldAu(&bar[132]) < bgen) __builtin_amdgcn_s_sleep(2);
    }
    __syncthreads();
  }
  asm volatile("" ::: "memory");
}

__device__ __forceinline__ float blockReduceSum(float v, float* sRed, int tid) {
  for (int o = 32; o > 0; o >>= 1) v += __shfl_down(v, o, 64);
  __syncthreads();
  if ((tid & 63) == 0) sRed[tid >> 6] = v;
  __syncthreads();
  float r = sRed[0] + sRed[1] + sRed[2] + sRed[3];
  __syncthreads();   // safe immediate sRed reuse
  return r;
}

// A (reader scores -> exp partials) + C (writer score rows, transposed store)
__device__ __forceinline__ void stageAC(
    int g, int tid, int c0, const KParams& p,
    float (*sX)[EE], float (*sH2)[HSS], float* sRed,
    float* swdstT, float* evecg, float* esumg)
{
  const int h0 = tid, h1 = tid + TPB;
  // ---- A: reader hidden (both rows) + scores
  float A00=0.f,A01=0.f,A10=0.f,A11=0.f;
  for (int e = 0; e < EE; e += 2) {
    const float* w = p.Wr1 + (size_t)e*HSS;
    float x00=sX[0][e], x10=sX[1][e], x01=sX[0][e+1], x11=sX[1][e+1];
    float wa=w[h0], wb=w[h1], wc=w[HSS+h0], wd=w[HSS+h1];
    A00 += x00*wa; A01 += x10*wa;
    A10 += x00*wb; A11 += x10*wb;
    A00 += x01*wc; A01 += x11*wc;
    A10 += x01*wd; A11 += x11*wd;
  }
  float b0 = p.br1[h0], b1 = p.br1[h1], wr0 = p.Wr2[h0], wr1 = p.Wr2[h1];
  float hA0 = fmaxf(A00+b0, 0.f), hA1 = fmaxf(A01+b0, 0.f);
  float hB0 = fmaxf(A10+b1, 0.f), hB1 = fmaxf(A11+b1, 0.f);
  float sc0 = blockReduceSum(hA0*wr0 + hB0*wr1, sRed, tid) + p.br2[0];
  float sc1 = blockReduceSum(hA1*wr0 + hB1*wr1, sRed, tid) + p.br2[0];
  float es0 = expf(sc0), es1 = expf(sc1);
  if (tid < EE) stA(evecg + (size_t)g*EE + tid, es0*sX[0][tid] + es1*sX[1][tid]);
  if (tid == 0) stA(esumg + g, es0 + es1);
  // ---- C: writer hidden (both rows)
  float C00=0.f,C01=0.f,C10=0.f,C11=0.f;
  for (int e = 0; e < EE; e += 2) {
    const float* w = p.Ww1 + (size_t)e*HSS;
    float x00=sX[0][e], x10=sX[1][e], x01=sX[0][e+1], x11=sX[1][e+1];
    float wa=w[h0], wb=w[h1], wc=w[HSS+h0], wd=w[HSS+h1];
    C00 += x00*wa; C01 += x10*wa;
    C10 += x00*wb; C11 += x10*wb;
    C00 += x01*wc; C01 += x11*wc;
    C10 += x01*wd; C11 += x11*wd;
  }
  float bw0 = p.bw1[h0], bw1v = p.bw1[h1];
  sH2[0][h0] = fmaxf(C00+bw0, 0.f);  sH2[1][h0] = fmaxf(C01+bw0, 0.f);
  sH2[0][h1] = fmaxf(C10+bw1v, 0.f); sH2[1][h1] = fmaxf(C11+bw1v, 0.f);
  __syncthreads();
  // ---- writer score rows (transposed: SWT[col][row])
  {
    const int cc = tid;
    float q0=0.f, q1=0.f;
    for (int h = 0; h < HSS; h += 2) {
      float wa = p.Ww2[(size_t)h*MM+cc], wb = p.Ww2[(size_t)(h+1)*MM+cc];
      q0 += sH2[0][h]*wa + sH2[0][h+1]*wb;
      q1 += sH2[1][h]*wa + sH2[1][h+1]*wb;
    }
    float bb = p.bw2[cc];
    stA(swdstT + (size_t)cc*MM + c0,     q0 + bb);
    stA(swdstT + (size_t)cc*MM + c0 + 1, q1 + bb);
  }
  __syncthreads();
}

// Phase-1 worker: exp of 256 memory-row scores + denom partials + weighted partial sums
__device__ __forceinline__ void dBulk(
    int tid, int c0, int t, float* ws,
    float (*sEv)[MM], float* sRed, float (*sP)[EE], float* sD)
{
  float* swc = ws + OFF_SW + (size_t)(t&1)*MM*MM;
  float* mpc = ws + OFF_MP + (size_t)(t&1)*MM*EE;
  const int r = tid;
  float e0 = expf(ldA(swc + (size_t)c0*MM + r));
  float e1 = expf(ldA(swc + (size_t)(c0+1)*MM + r));
  sEv[0][r] = e0; sEv[1][r] = e1;
  float d0 = blockReduceSum(e0, sRed, tid);
  float d1 = blockReduceSum(e1, sRed, tid);
  if (tid == 0) { sD[0] = d0; sD[1] = d1; }
  __syncthreads();
  const int e = tid & (EE-1), hf = tid >> 7;
  const int rbase = hf*128;
  float a0a=0.f,a0b=0.f,a1a=0.f,a1b=0.f;
  float* mp = mpc + (size_t)rbase*EE + e;
  for (int rr = 0; rr < 128; rr += 2) {
    float xv0 = ldA(mp + (size_t)rr*EE);
    float xv1 = ldA(mp + (size_t)(rr+1)*EE);
    a0a += sEv[0][rbase+rr]   * xv0;
    a1a += sEv[1][rbase+rr]   * xv0;
    a0b += sEv[0][rbase+rr+1] * xv1;
    a1b += sEv[1][rbase+rr+1] * xv1;
  }
  sRed[tid]     = a0a + a0b;
  sRed[TPB+tid] = a1a + a1b;
  __syncthreads();
  if (tid < EE) {
    sP[0][tid] = sRed[tid]     + sRed[128+tid];
    sP[1][tid] = sRed[TPB+tid] + sRed[TPB+128+tid];
  }
  __syncthreads();
}

// Phase-2 worker: rows 0/1 contributions + renorm + PE + new memPE rows
__device__ __forceinline__ void dFinish(
    int tid, int c0, int t, const KParams& p, float* ws,
    float (*sX)[EE], float* sRed, float (*sP)[EE], float* sD,
    float* sMS2, float* sHms)
{
  if (tid < EE) sMS2[tid] = ldA(ws + OFF_MS2 + tid);
  sHms[tid]       = ldA(ws + OFF_HMS + tid);
  sHms[tid + TPB] = ldA(ws + OFF_HMS + TPB + tid);
  __syncthreads();
  float v0 = sHms[tid]*p.Ww2[(size_t)tid*MM + c0]   + sHms[tid+TPB]*p.Ww2[(size_t)(tid+TPB)*MM + c0];
  float v1 = sHms[tid]*p.Ww2[(size_t)tid*MM + c0+1] + sHms[tid+TPB]*p.Ww2[(size_t)(tid+TPB)*MM + c0+1];
  float sw10 = blockReduceSum(v0, sRed, tid) + p.bw2[c0];
  float sw11 = blockReduceSum(v1, sRed, tid) + p.bw2[c0+1];
  float ew10 = expf(sw10), ew11 = expf(sw11);
  float ew00 = expf(ldA(ws + OFF_W0 + (size_t)t*MM + c0));
  float ew01 = expf(ldA(ws + OFF_W0 + (size_t)t*MM + c0+1));
  float inv0 = 1.f / (sD[0] + ew00 + ew10);
  float inv1 = 1.f / (sD[1] + ew01 + ew11);
  if (tid < EE) {
    const float* st = p.state + (size_t)t*4;
    float se = st[0]*p.Wemb[tid] + st[1]*p.Wemb[EE+tid]
             + st[2]*p.Wemb[2*EE+tid] + st[3]*p.Wemb[3*EE+tid] + p.bemb[tid];
    sX[0][tid] = (sP[0][tid] + ew00*se + ew10*sMS2[tid]) * inv0;
    sX[1][tid] = (sP[1][tid] + ew01*se + ew11*sMS2[tid]) * inv1;
  }
  __syncthreads();
  if (tid < 128) {
    sRed[tid]     = sX[0][tid];
    sRed[128+tid] = sX[0][tid];
    sRed[256+tid] = sX[1][tid];
    sRed[384+tid] = sX[1][tid];
  }
  __syncthreads();
  for (int s = 64; s > 0; s >>= 1) {
    if (tid < s) {
      sRed[tid]     = fminf(sRed[tid], sRed[tid+s]);
      sRed[128+tid] = fmaxf(sRed[128+tid], sRed[128+tid+s]);
      sRed[256+tid] = fminf(sRed[256+tid], sRed[256+tid+s]);
      sRed[384+tid] = fmaxf(sRed[384+tid], sRed[384+tid+s]);
    }
    __syncthreads();
  }
  float mn0 = sRed[0], mx0 = sRed[128], mn1 = sRed[256], mx1 = sRed[384];
  __syncthreads();
  float* mpn = ws + OFF_MP + (size_t)((t+1)&1)*MM*EE;
  if (tid < EE) {
    float x0 = (sX[0][tid]-mn0)/(mx0-mn0) + ws[OFF_PE + (size_t)c0*EE + tid];
    float x1 = (sX[1][tid]-mn1)/(mx1-mn1) + ws[OFF_PE + (size_t)(c0+1)*EE + tid];
    stA(mpn + (size_t)c0*EE + tid, x0);
    stA(mpn + (size_t)(c0+1)*EE + tid, x1);
    sX[0][tid] = x0; sX[1][tid] = x1;
  }
  __syncthreads();
}

// Leader phase-1: mem_state -> h -> probs/val(out) -> p1 -> ms2 -> hms
__device__ __forceinline__ void leaderB(
    int tid, int t, const KParams& p, float* ws,
    float* sRed, float* sMS, float* sSE, float* sP1, float* sSmall)
{
  const float* st = p.state + (size_t)t*4;
  const float s0 = st[0], s1 = st[1], s2 = st[2], s3 = st[3];
  if (tid < EE)
    sSE[tid] = s0*p.Wemb[tid] + s1*p.Wemb[EE+tid]
             + s2*p.Wemb[2*EE+tid] + s3*p.Wemb[3*EE+tid] + p.bemb[tid];
  float er0 = expf(ldA(ws + OFF_R0 + t));
  float v = (tid < NWG) ? ldA(ws + OFF_ES + tid) : 0.f;
  float denom = er0 + blockReduceSum(v, sRed, tid);
  float invd = 1.f / denom;
  {
    const int e = tid & (EE-1), hh = tid >> 7;
    float acc = 0.f;
    const float* evp = ws + OFF_EV + (size_t)hh*64*EE + e;
    #pragma unroll 4
    for (int q = 0; q < 64; ++q) acc += ldA(evp + (size_t)q*EE);
    sRed[tid] = acc;
  }
  __syncthreads();
  if (tid < EE) sMS[tid] = (er0*sSE[tid] + sRed[tid] + sRed[128+tid]) * invd;
  __syncthreads();
  const int j0 = tid, j1 = tid + TPB;
  const float* cs  = ws + OFF_CS;
  const float* csb = ws + OFF_CBS;
  const float* cp  = ws + OFF_CP;
  const float* cpb = ws + OFF_CBP;
  // trunk h
  float a0=0.f,a1=0.f,a2=0.f,a3=0.f,b0=0.f,b1=0.f,b2=0.f,b3=0.f;
  for (int e = 0; e < EE; e += 4) {
    const float* w = p.Ws + (size_t)(EE+e)*HSS;
    float m0=sMS[e],m1=sMS[e+1],m2=sMS[e+2],m3=sMS[e+3];
    a0+=m0*w[j0];        b0+=m0*w[j1];
    a1+=m1*w[HSS+j0];    b1+=m1*w[HSS+j1];
    a2+=m2*w[2*HSS+j0];  b2+=m2*w[2*HSS+j1];
    a3+=m3*w[3*HSS+j0];  b3+=m3*w[3*HSS+j1];
  }
  float sh0a = s0*cs[j0] + s1*cs[HSS+j0] + s2*cs[2*HSS+j0] + s3*cs[3*HSS+j0] + csb[j0];
  float sh0b = s0*cs[j1] + s1*cs[HSS+j1] + s2*cs[2*HSS+j1] + s3*cs[3*HSS+j1] + csb[j1];
  float hv0 = fmaxf(sh0a + (a0+a1)+(a2+a3) + p.bs[j0], 0.f);
  float hv1 = fmaxf(sh0b + (b0+b1)+(b2+b3) + p.bs[j1], 0.f);
  float pa[6];
  #pragma unroll
  for (int aa = 0; aa < 5; ++aa) pa[aa] = hv0*p.Wa[(size_t)j0*5+aa] + hv1*p.Wa[(size_t)j1*5+aa];
  pa[5] = hv0*p.Wc[j0] + hv1*p.Wc[j1];
  #pragma unroll
  for (int aa = 0; aa < 6; ++aa) {
    float r = blockReduceSum(pa[aa], sRed, tid);
    if (tid == 0) sSmall[1+aa] = r;
  }
  __syncthreads();
  if (tid == 0) {
    float l0=sSmall[1]+p.ba[0], l1=sSmall[2]+p.ba[1], l2=sSmall[3]+p.ba[2];
    float l3=sSmall[4]+p.ba[3], l4=sSmall[5]+p.ba[4];
    float mx = fmaxf(fmaxf(fmaxf(l0,l1),fmaxf(l2,l3)), l4);
    float e0=expf(l0-mx),e1=expf(l1-mx),e2=expf(l2-mx),e3=expf(l3-mx),e4=expf(l4-mx);
    float is = 1.f/(e0+e1+e2+e3+e4);
    float p0=e0*is,p1=e1*is,p2=e2*is,p3=e3*is,p4=e4*is;
    p.out[(size_t)t*5+0]=p0; p.out[(size_t)t*5+1]=p1; p.out[(size_t)t*5+2]=p2;
    p.out[(size_t)t*5+3]=p3; p.out[(size_t)t*5+4]=p4;
    float val = sSmall[6] + p.bc[0];
    p.out[(size_t)BSZ*5 + t] = val;
    sSmall[1]=p0; sSmall[2]=p1; sSmall[3]=p2; sSmall[4]=p3; sSmall[5]=p4; sSmall[6]=val;
  }
  __syncthreads();
  // p1
  {
    const int k = tid;
    float acc = s0*cp[k] + s1*cp[HPP+k] + s2*cp[2*HPP+k] + s3*cp[3*HPP+k] + cpb[k] + p.bp1[k];
    float q0=0.f,q1=0.f,q2=0.f,q3=0.f;
    for (int e = 0; e < EE; e += 4) {
      const float* w = p.Wp1 + (size_t)(EE+e)*HPP;
      q0 += sMS[e]  * w[k];
      q1 += sMS[e+1]* w[HPP+k];
      q2 += sMS[e+2]* w[2*HPP+k];
      q3 += sMS[e+3]* w[3*HPP+k];
    }
    acc += (q0+q1)+(q2+q3);
    #pragma unroll
    for (int aa = 0; aa < 5; ++aa) acc += sSmall[1+aa] * p.Wp1[(size_t)(2*EE+aa)*HPP + k];
    acc += sSmall[6] * p.Wp1[(size_t)(2*EE+5)*HPP + k];
    sP1[k] = fmaxf(acc, 0.f);
  }
  __syncthreads();
  // ms2
  if (tid < EE) {
    float q0=0.f,q1=0.f,q2=0.f,q3=0.f;
    for (int k = 0; k < HPP; k += 4) {
      q0 += sP1[k]  * p.Wp2[(size_t) k   *EE + tid];
      q1 += sP1[k+1]* p.Wp2[(size_t)(k+1)*EE + tid];
      q2 += sP1[k+2]* p.Wp2[(size_t)(k+2)*EE + tid];
      q3 += sP1[k+3]* p.Wp2[(size_t)(k+3)*EE + tid];
    }
    float m = (q0+q1)+(q2+q3) + p.bp2[tid];
    sMS[tid] = m;
    stA(ws + OFF_MS2 + tid, m);
  }
  __syncthreads();
  // hms = relu(ms2 @ Ww1 + bw1)
  {
    float c0a=0.f,c1a=0.f,c2a=0.f,c3a=0.f,d0=0.f,d1=0.f,d2=0.f,d3=0.f;
    for (int e = 0; e < EE; e += 4) {
      const float* w = p.Ww1 + (size_t)e*HSS;
      float m0=sMS[e],m1=sMS[e+1],m2=sMS[e+2],m3=sMS[e+3];
      c0a+=m0*w[j0];       d0+=m0*w[j1];
      c1a+=m1*w[HSS+j0];   d1+=m1*w[HSS+j1];
      c2a+=m2*w[2*HSS+j0]; d2+=m2*w[2*HSS+j1];
      c3a+=m3*w[3*HSS+j0]; d3+=m3*w[3*HSS+j1];
    }
    stA(ws + OFF_HMS + j0, fmaxf((c0a+c1a)+(c2a+c3a) + p.bw1[j0], 0.f));
    stA(ws + OFF_HMS + j1, fmaxf((d0+d1)+(d2+d3) + p.bw1[j1], 0.f));
  }
}

__global__ __launch_bounds__(TPB)
void toyac_kernel(KParams p) {
  const int g = blockIdx.x;
  const int tid = threadIdx.x;
  const int c0 = 2*g;
  float* ws = p.ws;
  unsigned* bar = (unsigned*)p.ws;

  __shared__ float sX[2][EE];
  __shared__ float sH2[2][HSS];
  __shared__ float sRed[2*TPB];
  __shared__ float sEv[2][MM];
  __shared__ float sP[2][EE];
  __shared__ float sD[2];
  __shared__ float sMS[EE];
  __shared__ float sSE[EE];
  __shared__ float sMS2[EE];
  __shared__ float sP1[HPP];
  __shared__ float sHms[HSS];
  __shared__ float sSmall[16];

  unsigned bgen = 0;

  // ---------------- P0a ----------------
  if (g < NWG) {
    const int e = tid & (EE-1), j = tid >> 7, c = c0 + j;
    double dv = exp(-(double)(2*(e>>1)) * log(10000.0) / 128.0);
    double arg = (double)c * dv;
    float pev = ((e & 1) == 0) ? (float)sin(arg) : (float)cos(arg);
    ws[OFF_PE + (size_t)c*EE + e] = pev;                 // block-local use only
    float m0v = p.mem0[(size_t)c*EE + e] + pev;
    stA(ws + OFF_MP + (size_t)c*EE + e, m0v);
    sX[j][e] = m0v;
  } else {
    // leader: composed matrices (leader-local: normal stores/reads)
    for (int jj = tid; jj < HSS; jj += TPB) {
      float c0a=0.f,c1a=0.f,c2a=0.f,c3a=0.f,cb=0.f;
      for (int e = 0; e < EE; ++e) {
        float wv = p.Ws[(size_t)e*HSS + jj];
        c0a += p.Wemb[e]*wv; c1a += p.Wemb[EE+e]*wv;
        c2a += p.Wemb[2*EE+e]*wv; c3a += p.Wemb[3*EE+e]*wv;
        cb  += p.bemb[e]*wv;
      }
      ws[OFF_CS + jj] = c0a; ws[OFF_CS + HSS + jj] = c1a;
      ws[OFF_CS + 2*HSS + jj] = c2a; ws[OFF_CS + 3*HSS + jj] = c3a;
      ws[OFF_CBS + jj] = cb;
    }
    for (int k = tid; k < HPP; k += TPB) {
      float c0a=0.f,c1a=0.f,c2a=0.f,c3a=0.f,cb=0.f;
      for (int e = 0; e < EE; ++e) {
        float wv = p.Wp1[(size_t)e*HPP + k];
        c0a += p.Wemb[e]*wv; c1a += p.Wemb[EE+e]*wv;
        c2a += p.Wemb[2*EE+e]*wv; c3a += p.Wemb[3*EE+e]*wv;
        cb  += p.bemb[e]*wv;
      }
      ws[OFF_CP + k] = c0a; ws[OFF_CP + HPP + k] = c1a;
      ws[OFF_CP + 2*HPP + k] = c2a; ws[OFF_CP + 3*HPP + k] = c3a;
      ws[OFF_CBP + k] = cb;
    }
  }

  // ---------------- P0b: striped per-step R0, W0 ----------------
  const int j0 = tid, j1 = tid + TPB;
  for (int t = g; t < BSZ; t += NWGT) {
    __syncthreads();
    if (tid < EE) {
      const float* st = p.state + (size_t)t*4;
      sSE[tid] = st[0]*p.Wemb[tid] + st[1]*p.Wemb[EE+tid]
               + st[2]*p.Wemb[2*EE+tid] + st[3]*p.Wemb[3*EE+tid] + p.bemb[tid];
    }
    __syncthreads();
    { // r0
      float a0=0.f,a1=0.f,a2=0.f,a3=0.f,b0=0.f,b1=0.f,b2=0.f,b3=0.f;
      for (int e = 0; e < EE; e += 4) {
        const float* w = p.Wr1 + (size_t)e*HSS;
        float m0=sSE[e],m1=sSE[e+1],m2=sSE[e+2],m3=sSE[e+3];
        a0+=m0*w[j0];        b0+=m0*w[j1];
        a1+=m1*w[HSS+j0];    b1+=m1*w[HSS+j1];
        a2+=m2*w[2*HSS+j0];  b2+=m2*w[2*HSS+j1];
        a3+=m3*w[3*HSS+j0];  b3+=m3*w[3*HSS+j1];
      }
      float hr0 = fmaxf((a0+a1)+(a2+a3) + p.br1[j0], 0.f);
      float hr1 = fmaxf((b0+b1)+(b2+b3) + p.br1[j1], 0.f);
      float sc = blockReduceSum(hr0*p.Wr2[j0] + hr1*p.Wr2[j1], sRed, tid);
      if (tid == 0) stA(ws + OFF_R0 + t, sc + p.br2[0]);
    }
    { // w0 row (all 256 cols)
      float a0=0.f,a1=0.f,a2=0.f,a3=0.f,b0=0.f,b1=0.f,b2=0.f,b3=0.f;
      for (int e = 0; e < EE; e += 4) {
        const float* w = p.Ww1 + (size_t)e*HSS;
        float m0=sSE[e],m1=sSE[e+1],m2=sSE[e+2],m3=sSE[e+3];
        a0+=m0*w[j0];        b0+=m0*w[j1];
        a1+=m1*w[HSS+j0];    b1+=m1*w[HSS+j1];
        a2+=m2*w[2*HSS+j0];  b2+=m2*w[2*HSS+j1];
        a3+=m3*w[3*HSS+j0];  b3+=m3*w[3*HSS+j1];
      }
      sH2[0][j0] = fmaxf((a0+a1)+(a2+a3) + p.bw1[j0], 0.f);
      sH2[0][j1] = fmaxf((b0+b1)+(b2+b3) + p.bw1[j1], 0.f);
      __syncthreads();
      const int cc = tid;
      float q0=0.f,q1=0.f,q2=0.f,q3=0.f;
      for (int h = 0; h < HSS; h += 4) {
        q0 += sH2[0][h]  * p.Ww2[(size_t) h   *MM+cc];
        q1 += sH2[0][h+1]* p.Ww2[(size_t)(h+1)*MM+cc];
        q2 += sH2[0][h+2]* p.Ww2[(size_t)(h+2)*MM+cc];
        q3 += sH2[0][h+3]* p.Ww2[(size_t)(h+3)*MM+cc];
      }
      stA(ws + OFF_W0 + (size_t)t*MM + cc, (q0+q1)+(q2+q3) + p.bw2[cc]);
    }
  }

  // prologue: scores + reader partials for step 0
  if (g < NWG) {
    __syncthreads();
    stageAC(g, tid, c0, p, sX, sH2, sRed, ws + OFF_SW, ws + OFF_EV, ws + OFF_ES);
  }
  wsBarrier(bar, g, tid, ++bgen);

  // ---------------- main sequential loop ----------------
  for (int t = 0; t < BSZ; ++t) {
    if (g == LEADER) {
      leaderB(tid, t, p, ws, sRed, sMS, sSE, sP1, sSmall);
    } else {
      dBulk(tid, c0, t, ws, sEv, sRed, sP, sD);
    }
    wsBarrier(bar, g, tid, ++bgen);
    if (g < NWG && t < BSZ - 1) {
      dFinish(tid, c0, t, p, ws, sX, sRed, sP, sD, sMS2, sHms);
      stageAC(g, tid, c0, p, sX, sH2, sRed,
              ws + OFF_SW + (size_t)((t+1)&1)*MM*MM, ws + OFF_EV, ws + OFF_ES);
    }
    wsBarrier(bar, g, tid, ++bgen);
  }
}

extern "C" void kernel_launch(void* const* d_in, const int* in_sizes, int n_in,
                              void* d_out, int out_size, void* d_ws, size_t ws_size,
                              hipStream_t stream) {
  hipMemsetAsync(d_ws, 0, 2048, stream);  // barrier flags/release
  KParams kp;
  kp.state = (const float*)d_in[0];
  kp.mem0  = (const float*)d_in[1];
  kp.Wemb  = (const float*)d_in[2];
  kp.bemb  = (const float*)d_in[3];
  kp.Wr1   = (const float*)d_in[4];
  kp.br1   = (const float*)d_in[5];
  kp.Wr2   = (const float*)d_in[6];
  kp.br2   = (const float*)d_in[7];
  kp.Ww1   = (const float*)d_in[8];
  kp.bw1   = (const float*)d_in[9];
  kp.Ww2   = (const float*)d_in[10];
  kp.bw2   = (const float*)d_in[11];
  kp.Ws    = (const float*)d_in[12];
  kp.bs    = (const float*)d_in[13];
  kp.Wa    = (const float*)d_in[14];
  kp.ba    = (const float*)d_in[15];
  kp.Wc    = (const float*)d_in[16];
  kp.bc    = (const float*)d_in[17];
  kp.Wp1   = (const float*)d_in[18];
  kp.bp1   = (const float*)d_in[19];
  kp.Wp2   = (const float*)d_in[20];
  kp.bp2   = (const float*)d_in[21];
  kp.out   = (float*)d_out;
  kp.ws    = (float*)d_ws;
  toyac_kernel<<<dim3(NWGT), dim3(TPB), 0, stream>>>(kp);
}

// Round 4
// 218094.165 us; speedup vs baseline: 8.1238x; 1.1067x over previous
//
#include <hip/hip_runtime.h>
#include <math.h>

#define BSZ 2048   // batch steps
#define MM  256    // memory slots
#define EE  128    // embedding dim
#define HSS 512    // summarizer hidden
#define HPP 256    // processor hidden
#define NWG 128    // worker blocks (2 memory rows each)
#define NWGT 129   // workers + 1 leader
#define LEADER 128
#define TPB 256

typedef float f4 __attribute__((ext_vector_type(4)));
typedef float f2 __attribute__((ext_vector_type(2)));

// workspace offsets (floats). First 512 floats: barrier flags/release (memset 0).
#define OFF_PE   512
#define OFF_R0   (OFF_PE + MM*EE)
#define OFF_W0   (OFF_R0 + BSZ)
#define OFF_MP   (OFF_W0 + BSZ*MM)        // memPE double buffer: 2*MM*EE
#define OFF_SW   (OFF_MP + 2*MM*EE)       // writer scores ROW-MAJOR [buf][row][col]: 2*MM*MM
#define OFF_EV   (OFF_SW + 2*MM*MM)       // per-WG exp-weighted partials: NWG*EE
#define OFF_ES   (OFF_EV + NWG*EE)        // per-WG exp sums: NWG
#define OFF_MS2  (OFF_ES + NWG)           // ms2: EE
#define OFF_HMS  (OFF_MS2 + EE)           // relu(ms2@Ww1+bw1): HSS
#define OFF_CS   (OFF_HMS + HSS)          // Wemb@Ws[0:128,:]: 4*HSS (leader-local)
#define OFF_CBS  (OFF_CS + 4*HSS)         // bemb@Ws[0:128,:]: HSS
#define OFF_CP   (OFF_CBS + HSS)          // Wemb@Wp1[0:128,:]: 4*HPP
#define OFF_CBP  (OFF_CP + 4*HPP)         // bemb@Wp1[0:128,:]: HPP

struct KParams {
  const float *state, *mem0, *Wemb, *bemb, *Wr1, *br1, *Wr2, *br2;
  const float *Ww1, *bw1, *Ww2, *bw2, *Ws, *bs, *Wa, *ba, *Wc, *bc;
  const float *Wp1, *bp1, *Wp2, *bp2;
  float *out;
  float *ws;
};

// ---- relaxed agent-scope scalar ops (coherent across XCDs, no cache maintenance) ----
__device__ __forceinline__ float ldA(const float* p) {
  return __hip_atomic_load(p, __ATOMIC_RELAXED, __HIP_MEMORY_SCOPE_AGENT);
}
__device__ __forceinline__ void stA(float* p, float v) {
  __hip_atomic_store(p, v, __ATOMIC_RELAXED, __HIP_MEMORY_SCOPE_AGENT);
}
__device__ __forceinline__ unsigned ldAu(const unsigned* p) {
  return __hip_atomic_load(p, __ATOMIC_RELAXED, __HIP_MEMORY_SCOPE_AGENT);
}
__device__ __forceinline__ void stAu(unsigned* p, unsigned v) {
  __hip_atomic_store(p, v, __ATOMIC_RELAXED, __HIP_MEMORY_SCOPE_AGENT);
}

// ---- batched L1/L2-bypass loads: 8 independent dwordx4, ONE waitcnt ----
__device__ __forceinline__ void ldA4x8(const float* p, int strideF, f4* v) {
  const float* p1 = p + strideF;
  const float* p2 = p + 2*strideF;
  const float* p3 = p + 3*strideF;
  const float* p4 = p + 4*strideF;
  const float* p5 = p + 5*strideF;
  const float* p6 = p + 6*strideF;
  const float* p7 = p + 7*strideF;
  asm volatile(
    "global_load_dwordx4 %0, %8, off sc0 sc1\n\t"
    "global_load_dwordx4 %1, %9, off sc0 sc1\n\t"
    "global_load_dwordx4 %2, %10, off sc0 sc1\n\t"
    "global_load_dwordx4 %3, %11, off sc0 sc1\n\t"
    "global_load_dwordx4 %4, %12, off sc0 sc1\n\t"
    "global_load_dwordx4 %5, %13, off sc0 sc1\n\t"
    "global_load_dwordx4 %6, %14, off sc0 sc1\n\t"
    "global_load_dwordx4 %7, %15, off sc0 sc1\n\t"
    "s_waitcnt vmcnt(0)"
    : "=&v"(v[0]), "=&v"(v[1]), "=&v"(v[2]), "=&v"(v[3]),
      "=&v"(v[4]), "=&v"(v[5]), "=&v"(v[6]), "=&v"(v[7])
    : "v"(p), "v"(p1), "v"(p2), "v"(p3), "v"(p4), "v"(p5), "v"(p6), "v"(p7)
    : "memory");
}
__device__ __forceinline__ f2 ldA2(const float* p) {
  f2 r;
  asm volatile("global_load_dwordx2 %0, %1, off sc0 sc1\n\ts_waitcnt vmcnt(0)"
    : "=&v"(r) : "v"(p) : "memory");
  return r;
}

// flag-tree grid barrier: relaxed atomics only; ordering via vmcnt drain + s_barrier
__device__ __forceinline__ void wsBarrier(unsigned* bar, int g, int tid, unsigned bgen) {
  asm volatile("s_waitcnt vmcnt(0)" ::: "memory");
  __syncthreads();
  if (g == LEADER) {
    if (tid < NWG) {
      while (ldAu(&bar[tid]) < bgen) __builtin_amdgcn_s_sleep(2);
    }
    __syncthreads();
    if (tid == 0) stAu(&bar[132], bgen);
  } else {
    if (tid == 0) {
      stAu(&bar[g], bgen);
      while (ldAu(&bar[132]) < bgen) __builtin_amdgcn_s_sleep(2);
    }
    __syncthreads();
  }
  asm volatile("" ::: "memory");
}

__device__ __forceinline__ float blockReduceSum(float v, float* sRed, int tid) {
  for (int o = 32; o > 0; o >>= 1) v += __shfl_down(v, o, 64);
  __syncthreads();
  if ((tid & 63) == 0) sRed[tid >> 6] = v;
  __syncthreads();
  float r = sRed[0] + sRed[1] + sRed[2] + sRed[3];
  __syncthreads();
  return r;
}

// A (reader scores -> exp partials) + C (writer score rows, ROW-MAJOR coalesced store)
__device__ __forceinline__ void stageAC(
    int g, int tid, int c0, const KParams& p,
    float (*sX)[EE], float (*sH2)[HSS], float* sRed,
    float* swdst, float* evecg, float* esumg)
{
  const int h0 = tid, h1 = tid + TPB;
  float A00=0.f,A01=0.f,A10=0.f,A11=0.f;
  for (int e = 0; e < EE; e += 2) {
    const float* w = p.Wr1 + (size_t)e*HSS;
    float x00=sX[0][e], x10=sX[1][e], x01=sX[0][e+1], x11=sX[1][e+1];
    float wa=w[h0], wb=w[h1], wc=w[HSS+h0], wd=w[HSS+h1];
    A00 += x00*wa; A01 += x10*wa;
    A10 += x00*wb; A11 += x10*wb;
    A00 += x01*wc; A01 += x11*wc;
    A10 += x01*wd; A11 += x11*wd;
  }
  float b0 = p.br1[h0], b1 = p.br1[h1], wr0 = p.Wr2[h0], wr1 = p.Wr2[h1];
  float hA0 = fmaxf(A00+b0, 0.f), hA1 = fmaxf(A01+b0, 0.f);
  float hB0 = fmaxf(A10+b1, 0.f), hB1 = fmaxf(A11+b1, 0.f);
  float sc0 = blockReduceSum(hA0*wr0 + hB0*wr1, sRed, tid) + p.br2[0];
  float sc1 = blockReduceSum(hA1*wr0 + hB1*wr1, sRed, tid) + p.br2[0];
  float es0 = expf(sc0), es1 = expf(sc1);
  if (tid < EE) stA(evecg + (size_t)g*EE + tid, es0*sX[0][tid] + es1*sX[1][tid]);
  if (tid == 0) stA(esumg + g, es0 + es1);
  float C00=0.f,C01=0.f,C10=0.f,C11=0.f;
  for (int e = 0; e < EE; e += 2) {
    const float* w = p.Ww1 + (size_t)e*HSS;
    float x00=sX[0][e], x10=sX[1][e], x01=sX[0][e+1], x11=sX[1][e+1];
    float wa=w[h0], wb=w[h1], wc=w[HSS+h0], wd=w[HSS+h1];
    C00 += x00*wa; C01 += x10*wa;
    C10 += x00*wb; C11 += x10*wb;
    C00 += x01*wc; C01 += x11*wc;
    C10 += x01*wd; C11 += x11*wd;
  }
  float bw0 = p.bw1[h0], bw1v = p.bw1[h1];
  sH2[0][h0] = fmaxf(C00+bw0, 0.f);  sH2[1][h0] = fmaxf(C01+bw0, 0.f);
  sH2[0][h1] = fmaxf(C10+bw1v, 0.f); sH2[1][h1] = fmaxf(C11+bw1v, 0.f);
  __syncthreads();
  {
    const int cc = tid;
    float q0=0.f, q1=0.f;
    for (int h = 0; h < HSS; h += 2) {
      float wa = p.Ww2[(size_t)h*MM+cc], wb = p.Ww2[(size_t)(h+1)*MM+cc];
      q0 += sH2[0][h]*wa + sH2[0][h+1]*wb;
      q1 += sH2[1][h]*wa + sH2[1][h+1]*wb;
    }
    float bb = p.bw2[cc];
    // ROW-MAJOR: consecutive threads -> consecutive addresses (wave-coalesced)
    stA(swdst + (size_t)c0*MM + cc,     q0 + bb);
    stA(swdst + (size_t)(c0+1)*MM + cc, q1 + bb);
  }
  __syncthreads();
}

// Phase-1 worker: exp of 256 scores (own 2 cols) + denoms + weighted partial sums
__device__ __forceinline__ void dBulk(
    int tid, int c0, int t, float* ws,
    float (*sEv)[MM], float* sRed, float (*sP)[EE], float* sD,
    float (*sPart)[8][EE])
{
  float* swc = ws + OFF_SW + (size_t)(t&1)*MM*MM;
  float* mpc = ws + OFF_MP + (size_t)(t&1)*MM*EE;
  {
    f2 s = ldA2(swc + (size_t)tid*MM + c0);   // row tid, cols c0,c0+1
    float e0 = expf(s.x), e1 = expf(s.y);
    sEv[0][tid] = e0; sEv[1][tid] = e1;
    float d0 = blockReduceSum(e0, sRed, tid);
    float d1 = blockReduceSum(e1, sRed, tid);
    if (tid == 0) { sD[0] = d0; sD[1] = d1; }
  }
  __syncthreads();
  // weighted sums: thread = (e4 = (tid&31)*4, rg = tid>>5 -> rows rg*32..+31)
  const int e4 = (tid & 31) * 4, rg = tid >> 5;
  f4 acc0 = {0.f,0.f,0.f,0.f}, acc1 = {0.f,0.f,0.f,0.f};
  const float* base = mpc + (size_t)(rg*32)*EE + e4;
  #pragma unroll
  for (int b = 0; b < 4; ++b) {
    f4 v[8];
    ldA4x8(base + (size_t)b*8*EE, EE, v);
    const int r0b = rg*32 + b*8;
    #pragma unroll
    for (int i = 0; i < 8; ++i) {
      float w0 = sEv[0][r0b+i], w1 = sEv[1][r0b+i];
      acc0 += w0 * v[i];
      acc1 += w1 * v[i];
    }
  }
  #pragma unroll
  for (int k = 0; k < 4; ++k) {
    sPart[0][rg][e4+k] = acc0[k];
    sPart[1][rg][e4+k] = acc1[k];
  }
  __syncthreads();
  {
    const int e = tid & (EE-1), row = tid >> 7;
    float s = 0.f;
    #pragma unroll
    for (int rr = 0; rr < 8; ++rr) s += sPart[row][rr][e];
    sP[row][e] = s;
  }
  __syncthreads();
}

// Phase-2 worker: rows 0/1 contributions + renorm + PE + new memPE rows
__device__ __forceinline__ void dFinish(
    int tid, int c0, int t, const KParams& p, float* ws,
    float (*sX)[EE], float* sRed, float (*sP)[EE], float* sD,
    float* sMS2, float* sHms)
{
  if (tid < EE) sMS2[tid] = ldA(ws + OFF_MS2 + tid);
  sHms[tid]       = ldA(ws + OFF_HMS + tid);
  sHms[tid + TPB] = ldA(ws + OFF_HMS + TPB + tid);
  __syncthreads();
  float v0 = sHms[tid]*p.Ww2[(size_t)tid*MM + c0]   + sHms[tid+TPB]*p.Ww2[(size_t)(tid+TPB)*MM + c0];
  float v1 = sHms[tid]*p.Ww2[(size_t)tid*MM + c0+1] + sHms[tid+TPB]*p.Ww2[(size_t)(tid+TPB)*MM + c0+1];
  float sw10 = blockReduceSum(v0, sRed, tid) + p.bw2[c0];
  float sw11 = blockReduceSum(v1, sRed, tid) + p.bw2[c0+1];
  float ew10 = expf(sw10), ew11 = expf(sw11);
  float ew00 = expf(ldA(ws + OFF_W0 + (size_t)t*MM + c0));
  float ew01 = expf(ldA(ws + OFF_W0 + (size_t)t*MM + c0+1));
  float inv0 = 1.f / (sD[0] + ew00 + ew10);
  float inv1 = 1.f / (sD[1] + ew01 + ew11);
  if (tid < EE) {
    const float* st = p.state + (size_t)t*4;
    float se = st[0]*p.Wemb[tid] + st[1]*p.Wemb[EE+tid]
             + st[2]*p.Wemb[2*EE+tid] + st[3]*p.Wemb[3*EE+tid] + p.bemb[tid];
    sX[0][tid] = (sP[0][tid] + ew00*se + ew10*sMS2[tid]) * inv0;
    sX[1][tid] = (sP[1][tid] + ew01*se + ew11*sMS2[tid]) * inv1;
  }
  __syncthreads();
  if (tid < 128) {
    sRed[tid]     = sX[0][tid];
    sRed[128+tid] = sX[0][tid];
    sRed[256+tid] = sX[1][tid];
    sRed[384+tid] = sX[1][tid];
  }
  __syncthreads();
  for (int s = 64; s > 0; s >>= 1) {
    if (tid < s) {
      sRed[tid]     = fminf(sRed[tid], sRed[tid+s]);
      sRed[128+tid] = fmaxf(sRed[128+tid], sRed[128+tid+s]);
      sRed[256+tid] = fminf(sRed[256+tid], sRed[256+tid+s]);
      sRed[384+tid] = fmaxf(sRed[384+tid], sRed[384+tid+s]);
    }
    __syncthreads();
  }
  float mn0 = sRed[0], mx0 = sRed[128], mn1 = sRed[256], mx1 = sRed[384];
  __syncthreads();
  float* mpn = ws + OFF_MP + (size_t)((t+1)&1)*MM*EE;
  if (tid < EE) {
    float x0 = (sX[0][tid]-mn0)/(mx0-mn0) + ws[OFF_PE + (size_t)c0*EE + tid];
    float x1 = (sX[1][tid]-mn1)/(mx1-mn1) + ws[OFF_PE + (size_t)(c0+1)*EE + tid];
    stA(mpn + (size_t)c0*EE + tid, x0);
    stA(mpn + (size_t)(c0+1)*EE + tid, x1);
    sX[0][tid] = x0; sX[1][tid] = x1;
  }
  __syncthreads();
}

// Leader phase-1: mem_state -> h -> probs/val(out) -> p1 -> ms2 -> hms
__device__ __forceinline__ void leaderB(
    int tid, int t, const KParams& p, float* ws,
    float* sRed, float* sMS, float* sSE, float* sP1, float* sSmall,
    float (*sPart)[8][EE])
{
  const float* st = p.state + (size_t)t*4;
  const float s0 = st[0], s1 = st[1], s2 = st[2], s3 = st[3];
  if (tid < EE)
    sSE[tid] = s0*p.Wemb[tid] + s1*p.Wemb[EE+tid]
             + s2*p.Wemb[2*EE+tid] + s3*p.Wemb[3*EE+tid] + p.bemb[tid];
  float er0 = expf(ldA(ws + OFF_R0 + t));
  float v = (tid < NWG) ? ldA(ws + OFF_ES + tid) : 0.f;
  float denom = er0 + blockReduceSum(v, sRed, tid);
  float invd = 1.f / denom;
  // EV reduction: thread = (e4=(tid&31)*4, qg=tid>>5 -> q's qg*16..+15), batched bypass loads
  {
    const int e4 = (tid & 31) * 4, qg = tid >> 5;
    f4 acc = {0.f,0.f,0.f,0.f};
    const float* basep = ws + OFF_EV + (size_t)(qg*16)*EE + e4;
    f4 vv[8];
    ldA4x8(basep, EE, vv);
    #pragma unroll
    for (int i = 0; i < 8; ++i) acc += vv[i];
    ldA4x8(basep + 8*EE, EE, vv);
    #pragma unroll
    for (int i = 0; i < 8; ++i) acc += vv[i];
    #pragma unroll
    for (int k = 0; k < 4; ++k) sPart[0][qg][e4+k] = acc[k];
  }
  __syncthreads();
  if (tid < EE) {
    float s = 0.f;
    #pragma unroll
    for (int rr = 0; rr < 8; ++rr) s += sPart[0][rr][tid];
    sMS[tid] = (er0*sSE[tid] + s) * invd;
  }
  __syncthreads();
  const int j0 = tid, j1 = tid + TPB;
  const float* cs  = ws + OFF_CS;
  const float* csb = ws + OFF_CBS;
  const float* cp  = ws + OFF_CP;
  const float* cpb = ws + OFF_CBP;
  float a0=0.f,a1=0.f,a2=0.f,a3=0.f,b0=0.f,b1=0.f,b2=0.f,b3=0.f;
  for (int e = 0; e < EE; e += 4) {
    const float* w = p.Ws + (size_t)(EE+e)*HSS;
    float m0=sMS[e],m1=sMS[e+1],m2=sMS[e+2],m3=sMS[e+3];
    a0+=m0*w[j0];        b0+=m0*w[j1];
    a1+=m1*w[HSS+j0];    b1+=m1*w[HSS+j1];
    a2+=m2*w[2*HSS+j0];  b2+=m2*w[2*HSS+j1];
    a3+=m3*w[3*HSS+j0];  b3+=m3*w[3*HSS+j1];
  }
  float sh0a = s0*cs[j0] + s1*cs[HSS+j0] + s2*cs[2*HSS+j0] + s3*cs[3*HSS+j0] + csb[j0];
  float sh0b = s0*cs[j1] + s1*cs[HSS+j1] + s2*cs[2*HSS+j1] + s3*cs[3*HSS+j1] + csb[j1];
  float hv0 = fmaxf(sh0a + (a0+a1)+(a2+a3) + p.bs[j0], 0.f);
  float hv1 = fmaxf(sh0b + (b0+b1)+(b2+b3) + p.bs[j1], 0.f);
  float pa[6];
  #pragma unroll
  for (int aa = 0; aa < 5; ++aa) pa[aa] = hv0*p.Wa[(size_t)j0*5+aa] + hv1*p.Wa[(size_t)j1*5+aa];
  pa[5] = hv0*p.Wc[j0] + hv1*p.Wc[j1];
  #pragma unroll
  for (int aa = 0; aa < 6; ++aa) {
    float r = blockReduceSum(pa[aa], sRed, tid);
    if (tid == 0) sSmall[1+aa] = r;
  }
  __syncthreads();
  if (tid == 0) {
    float l0=sSmall[1]+p.ba[0], l1=sSmall[2]+p.ba[1], l2=sSmall[3]+p.ba[2];
    float l3=sSmall[4]+p.ba[3], l4=sSmall[5]+p.ba[4];
    float mx = fmaxf(fmaxf(fmaxf(l0,l1),fmaxf(l2,l3)), l4);
    float e0=expf(l0-mx),e1=expf(l1-mx),e2=expf(l2-mx),e3=expf(l3-mx),e4v=expf(l4-mx);
    float is = 1.f/(e0+e1+e2+e3+e4v);
    float p0=e0*is,p1=e1*is,p2=e2*is,p3=e3*is,p4=e4v*is;
    p.out[(size_t)t*5+0]=p0; p.out[(size_t)t*5+1]=p1; p.out[(size_t)t*5+2]=p2;
    p.out[(size_t)t*5+3]=p3; p.out[(size_t)t*5+4]=p4;
    float val = sSmall[6] + p.bc[0];
    p.out[(size_t)BSZ*5 + t] = val;
    sSmall[1]=p0; sSmall[2]=p1; sSmall[3]=p2; sSmall[4]=p3; sSmall[5]=p4; sSmall[6]=val;
  }
  __syncthreads();
  {
    const int k = tid;
    float acc = s0*cp[k] + s1*cp[HPP+k] + s2*cp[2*HPP+k] + s3*cp[3*HPP+k] + cpb[k] + p.bp1[k];
    float q0=0.f,q1=0.f,q2=0.f,q3=0.f;
    for (int e = 0; e < EE; e += 4) {
      const float* w = p.Wp1 + (size_t)(EE+e)*HPP;
      q0 += sMS[e]  * w[k];
      q1 += sMS[e+1]* w[HPP+k];
      q2 += sMS[e+2]* w[2*HPP+k];
      q3 += sMS[e+3]* w[3*HPP+k];
    }
    acc += (q0+q1)+(q2+q3);
    #pragma unroll
    for (int aa = 0; aa < 5; ++aa) acc += sSmall[1+aa] * p.Wp1[(size_t)(2*EE+aa)*HPP + k];
    acc += sSmall[6] * p.Wp1[(size_t)(2*EE+5)*HPP + k];
    sP1[k] = fmaxf(acc, 0.f);
  }
  __syncthreads();
  if (tid < EE) {
    float q0=0.f,q1=0.f,q2=0.f,q3=0.f;
    for (int k = 0; k < HPP; k += 4) {
      q0 += sP1[k]  * p.Wp2[(size_t) k   *EE + tid];
      q1 += sP1[k+1]* p.Wp2[(size_t)(k+1)*EE + tid];
      q2 += sP1[k+2]* p.Wp2[(size_t)(k+2)*EE + tid];
      q3 += sP1[k+3]* p.Wp2[(size_t)(k+3)*EE + tid];
    }
    float m = (q0+q1)+(q2+q3) + p.bp2[tid];
    sMS[tid] = m;
    stA(ws + OFF_MS2 + tid, m);
  }
  __syncthreads();
  {
    float c0a=0.f,c1a=0.f,c2a=0.f,c3a=0.f,d0=0.f,d1=0.f,d2=0.f,d3=0.f;
    for (int e = 0; e < EE; e += 4) {
      const float* w = p.Ww1 + (size_t)e*HSS;
      float m0=sMS[e],m1=sMS[e+1],m2=sMS[e+2],m3=sMS[e+3];
      c0a+=m0*w[j0];       d0+=m0*w[j1];
      c1a+=m1*w[HSS+j0];   d1+=m1*w[HSS+j1];
      c2a+=m2*w[2*HSS+j0]; d2+=m2*w[2*HSS+j1];
      c3a+=m3*w[3*HSS+j0]; d3+=m3*w[3*HSS+j1];
    }
    stA(ws + OFF_HMS + j0, fmaxf((c0a+c1a)+(c2a+c3a) + p.bw1[j0], 0.f));
    stA(ws + OFF_HMS + j1, fmaxf((d0+d1)+(d2+d3) + p.bw1[j1], 0.f));
  }
}

__global__ __launch_bounds__(TPB)
void toyac_kernel(KParams p) {
  const int g = blockIdx.x;
  const int tid = threadIdx.x;
  const int c0 = 2*g;
  float* ws = p.ws;
  unsigned* bar = (unsigned*)p.ws;

  __shared__ float sX[2][EE];
  __shared__ float sH2[2][HSS];
  __shared__ float sRed[2*TPB];
  __shared__ float sEv[2][MM];
  __shared__ float sPart[2][8][EE];
  __shared__ float sP[2][EE];
  __shared__ float sD[2];
  __shared__ float sMS[EE];
  __shared__ float sSE[EE];
  __shared__ float sMS2[EE];
  __shared__ float sP1[HPP];
  __shared__ float sHms[HSS];
  __shared__ float sSmall[16];

  unsigned bgen = 0;

  // ---------------- P0a ----------------
  if (g < NWG) {
    const int e = tid & (EE-1), j = tid >> 7, c = c0 + j;
    double dv = exp(-(double)(2*(e>>1)) * log(10000.0) / 128.0);
    double arg = (double)c * dv;
    float pev = ((e & 1) == 0) ? (float)sin(arg) : (float)cos(arg);
    ws[OFF_PE + (size_t)c*EE + e] = pev;
    float m0v = p.mem0[(size_t)c*EE + e] + pev;
    stA(ws + OFF_MP + (size_t)c*EE + e, m0v);
    sX[j][e] = m0v;
  } else {
    for (int jj = tid; jj < HSS; jj += TPB) {
      float c0a=0.f,c1a=0.f,c2a=0.f,c3a=0.f,cb=0.f;
      for (int e = 0; e < EE; ++e) {
        float wv = p.Ws[(size_t)e*HSS + jj];
        c0a += p.Wemb[e]*wv; c1a += p.Wemb[EE+e]*wv;
        c2a += p.Wemb[2*EE+e]*wv; c3a += p.Wemb[3*EE+e]*wv;
        cb  += p.bemb[e]*wv;
      }
      ws[OFF_CS + jj] = c0a; ws[OFF_CS + HSS + jj] = c1a;
      ws[OFF_CS + 2*HSS + jj] = c2a; ws[OFF_CS + 3*HSS + jj] = c3a;
      ws[OFF_CBS + jj] = cb;
    }
    for (int k = tid; k < HPP; k += TPB) {
      float c0a=0.f,c1a=0.f,c2a=0.f,c3a=0.f,cb=0.f;
      for (int e = 0; e < EE; ++e) {
        float wv = p.Wp1[(size_t)e*HPP + k];
        c0a += p.Wemb[e]*wv; c1a += p.Wemb[EE+e]*wv;
        c2a += p.Wemb[2*EE+e]*wv; c3a += p.Wemb[3*EE+e]*wv;
        cb  += p.bemb[e]*wv;
      }
      ws[OFF_CP + k] = c0a; ws[OFF_CP + HPP + k] = c1a;
      ws[OFF_CP + 2*HPP + k] = c2a; ws[OFF_CP + 3*HPP + k] = c3a;
      ws[OFF_CBP + k] = cb;
    }
  }

  // ---------------- P0b: striped per-step R0, W0 ----------------
  const int j0 = tid, j1 = tid + TPB;
  for (int t = g; t < BSZ; t += NWGT) {
    __syncthreads();
    if (tid < EE) {
      const float* st = p.state + (size_t)t*4;
      sSE[tid] = st[0]*p.Wemb[tid] + st[1]*p.Wemb[EE+tid]
               + st[2]*p.Wemb[2*EE+tid] + st[3]*p.Wemb[3*EE+tid] + p.bemb[tid];
    }
    __syncthreads();
    { // r0
      float a0=0.f,a1=0.f,a2=0.f,a3=0.f,b0=0.f,b1=0.f,b2=0.f,b3=0.f;
      for (int e = 0; e < EE; e += 4) {
        const float* w = p.Wr1 + (size_t)e*HSS;
        float m0=sSE[e],m1=sSE[e+1],m2=sSE[e+2],m3=sSE[e+3];
        a0+=m0*w[j0];        b0+=m0*w[j1];
        a1+=m1*w[HSS+j0];    b1+=m1*w[HSS+j1];
        a2+=m2*w[2*HSS+j0];  b2+=m2*w[2*HSS+j1];
        a3+=m3*w[3*HSS+j0];  b3+=m3*w[3*HSS+j1];
      }
      float hr0 = fmaxf((a0+a1)+(a2+a3) + p.br1[j0], 0.f);
      float hr1 = fmaxf((b0+b1)+(b2+b3) + p.br1[j1], 0.f);
      float sc = blockReduceSum(hr0*p.Wr2[j0] + hr1*p.Wr2[j1], sRed, tid);
      if (tid == 0) stA(ws + OFF_R0 + t, sc + p.br2[0]);
    }
    { // w0 row (all 256 cols)
      float a0=0.f,a1=0.f,a2=0.f,a3=0.f,b0=0.f,b1=0.f,b2=0.f,b3=0.f;
      for (int e = 0; e < EE; e += 4) {
        const float* w = p.Ww1 + (size_t)e*HSS;
        float m0=sSE[e],m1=sSE[e+1],m2=sSE[e+2],m3=sSE[e+3];
        a0+=m0*w[j0];        b0+=m0*w[j1];
        a1+=m1*w[HSS+j0];    b1+=m1*w[HSS+j1];
        a2+=m2*w[2*HSS+j0];  b2+=m2*w[2*HSS+j1];
        a3+=m3*w[3*HSS+j0];  b3+=m3*w[3*HSS+j1];
      }
      sH2[0][j0] = fmaxf((a0+a1)+(a2+a3) + p.bw1[j0], 0.f);
      sH2[0][j1] = fmaxf((b0+b1)+(b2+b3) + p.bw1[j1], 0.f);
      __syncthreads();
      const int cc = tid;
      float q0=0.f,q1=0.f,q2=0.f,q3=0.f;
      for (int h = 0; h < HSS; h += 4) {
        q0 += sH2[0][h]  * p.Ww2[(size_t) h   *MM+cc];
        q1 += sH2[0][h+1]* p.Ww2[(size_t)(h+1)*MM+cc];
        q2 += sH2[0][h+2]* p.Ww2[(size_t)(h+2)*MM+cc];
        q3 += sH2[0][h+3]* p.Ww2[(size_t)(h+3)*MM+cc];
      }
      stA(ws + OFF_W0 + (size_t)t*MM + cc, (q0+q1)+(q2+q3) + p.bw2[cc]);
    }
  }

  // prologue: scores + reader partials for step 0
  if (g < NWG) {
    __syncthreads();
    stageAC(g, tid, c0, p, sX, sH2, sRed, ws + OFF_SW, ws + OFF_EV, ws + OFF_ES);
  }
  wsBarrier(bar, g, tid, ++bgen);

  // ---------------- main sequential loop ----------------
  for (int t = 0; t < BSZ; ++t) {
    if (g == LEADER) {
      leaderB(tid, t, p, ws, sRed, sMS, sSE, sP1, sSmall, sPart);
    } else {
      dBulk(tid, c0, t, ws, sEv, sRed, sP, sD, sPart);
    }
    wsBarrier(bar, g, tid, ++bgen);
    if (g < NWG && t < BSZ - 1) {
      dFinish(tid, c0, t, p, ws, sX, sRed, sP, sD, sMS2, sHms);
      stageAC(g, tid, c0, p, sX, sH2, sRed,
              ws + OFF_SW + (size_t)((t+1)&1)*MM*MM, ws + OFF_EV, ws + OFF_ES);
    }
    wsBarrier(bar, g, tid, ++bgen);
  }
}

extern "C" void kernel_launch(void* const* d_in, const int* in_sizes, int n_in,
                              void* d_out, int out_size, void* d_ws, size_t ws_size,
                              hipStream_t stream) {
  hipMemsetAsync(d_ws, 0, 2048, stream);  // barrier flags/release
  KParams kp;
  kp.state = (const float*)d_in[0];
  kp.mem0  = (const float*)d_in[1];
  kp.Wemb  = (const float*)d_in[2];
  kp.bemb  = (const float*)d_in[3];
  kp.Wr1   = (const float*)d_in[4];
  kp.br1   = (const float*)d_in[5];
  kp.Wr2   = (const float*)d_in[6];
  kp.br2   = (const float*)d_in[7];
  kp.Ww1   = (const float*)d_in[8];
  kp.bw1   = (const float*)d_in[9];
  kp.Ww2   = (const float*)d_in[10];
  kp.bw2   = (const float*)d_in[11];
  kp.Ws    = (const float*)d_in[12];
  kp.bs    = (const float*)d_in[13];
  kp.Wa    = (const float*)d_in[14];
  kp.ba    = (const float*)d_in[15];
  kp.Wc    = (const float*)d_in[16];
  kp.bc    = (const float*)d_in[17];
  kp.Wp1   = (const float*)d_in[18];
  kp.bp1   = (const float*)d_in[19];
  kp.Wp2   = (const float*)d_in[20];
  kp.bp2   = (const float*)d_in[21];
  kp.out   = (float*)d_out;
  kp.ws    = (float*)d_ws;
  toyac_kernel<<<dim3(NWGT), dim3(TPB), 0, stream>>>(kp);
}

// Round 5
// 106359.619 us; speedup vs baseline: 16.6582x; 2.0505x over previous
//
#include <hip/hip_runtime.h>
#include <math.h>

#define BSZ 2048   // batch steps
#define MM  256    // memory slots
#define EE  128    // embedding dim
#define HSS 512    // summarizer hidden
#define HPP 256    // processor hidden
#define NWG 64     // worker blocks (4 memory rows each)
#define NWGT 65    // workers + 1 leader
#define LEADER 64
#define TPB 512
#define ROWS 4

typedef float f4 __attribute__((ext_vector_type(4)));

// workspace offsets (floats). First 512 floats: barrier flags/release (memset 0).
#define OFF_PE   512
#define OFF_R0   (OFF_PE + MM*EE)
#define OFF_W0   (OFF_R0 + BSZ)
#define OFF_MP   (OFF_W0 + BSZ*MM)        // memPE double buffer: 2*MM*EE
#define OFF_SW   (OFF_MP + 2*MM*EE)       // writer scores ROW-MAJOR [buf][row][col]: 2*MM*MM
#define OFF_EV   (OFF_SW + 2*MM*MM)       // per-WG exp-weighted partials: NWG*EE
#define OFF_ES   (OFF_EV + NWG*EE)        // per-WG exp sums: NWG
#define OFF_MS2  (OFF_ES + NWG)           // ms2: EE
#define OFF_HMS  (OFF_MS2 + EE)           // relu(ms2@Ww1+bw1): HSS
#define OFF_CS   (OFF_HMS + HSS)          // Wemb@Ws[0:128,:]: 4*HSS (leader-local)
#define OFF_CBS  (OFF_CS + 4*HSS)
#define OFF_CP   (OFF_CBS + HSS)          // Wemb@Wp1[0:128,:]: 4*HPP
#define OFF_CBP  (OFF_CP + 4*HPP)

struct KParams {
  const float *state, *mem0, *Wemb, *bemb, *Wr1, *br1, *Wr2, *br2;
  const float *Ww1, *bw1, *Ww2, *bw2, *Ws, *bs, *Wa, *ba, *Wc, *bc;
  const float *Wp1, *bp1, *Wp2, *bp2;
  float *out;
  float *ws;
};

// ---- relaxed agent-scope ops (coherent across XCDs, no cache maintenance) ----
__device__ __forceinline__ float ldA(const float* p) {
  return __hip_atomic_load(p, __ATOMIC_RELAXED, __HIP_MEMORY_SCOPE_AGENT);
}
__device__ __forceinline__ void stA(float* p, float v) {
  __hip_atomic_store(p, v, __ATOMIC_RELAXED, __HIP_MEMORY_SCOPE_AGENT);
}
__device__ __forceinline__ unsigned ldAu(const unsigned* p) {
  return __hip_atomic_load(p, __ATOMIC_RELAXED, __HIP_MEMORY_SCOPE_AGENT);
}
__device__ __forceinline__ void stAu(unsigned* p, unsigned v) {
  __hip_atomic_store(p, v, __ATOMIC_RELAXED, __HIP_MEMORY_SCOPE_AGENT);
}

// ---- batched L2-bypass vector loads: N independent dwordx4, ONE waitcnt ----
__device__ __forceinline__ void ldA4x8(const float* p, int strideF, f4* v) {
  const float *p1=p+strideF, *p2=p+2*strideF, *p3=p+3*strideF,
              *p4=p+4*strideF, *p5=p+5*strideF, *p6=p+6*strideF, *p7=p+7*strideF;
  asm volatile(
    "global_load_dwordx4 %0, %8, off sc0 sc1\n\t"
    "global_load_dwordx4 %1, %9, off sc0 sc1\n\t"
    "global_load_dwordx4 %2, %10, off sc0 sc1\n\t"
    "global_load_dwordx4 %3, %11, off sc0 sc1\n\t"
    "global_load_dwordx4 %4, %12, off sc0 sc1\n\t"
    "global_load_dwordx4 %5, %13, off sc0 sc1\n\t"
    "global_load_dwordx4 %6, %14, off sc0 sc1\n\t"
    "global_load_dwordx4 %7, %15, off sc0 sc1\n\t"
    "s_waitcnt vmcnt(0)"
    : "=&v"(v[0]), "=&v"(v[1]), "=&v"(v[2]), "=&v"(v[3]),
      "=&v"(v[4]), "=&v"(v[5]), "=&v"(v[6]), "=&v"(v[7])
    : "v"(p), "v"(p1), "v"(p2), "v"(p3), "v"(p4), "v"(p5), "v"(p6), "v"(p7)
    : "memory");
}
__device__ __forceinline__ void ldA4x4(const float* p, int strideF, f4* v) {
  const float *p1=p+strideF, *p2=p+2*strideF, *p3=p+3*strideF;
  asm volatile(
    "global_load_dwordx4 %0, %4, off sc0 sc1\n\t"
    "global_load_dwordx4 %1, %5, off sc0 sc1\n\t"
    "global_load_dwordx4 %2, %6, off sc0 sc1\n\t"
    "global_load_dwordx4 %3, %7, off sc0 sc1\n\t"
    "s_waitcnt vmcnt(0)"
    : "=&v"(v[0]), "=&v"(v[1]), "=&v"(v[2]), "=&v"(v[3])
    : "v"(p), "v"(p1), "v"(p2), "v"(p3)
    : "memory");
}
__device__ __forceinline__ f4 ldA4(const float* p) {
  f4 r;
  asm volatile("global_load_dwordx4 %0, %1, off sc0 sc1\n\ts_waitcnt vmcnt(0)"
    : "=&v"(r) : "v"(p) : "memory");
  return r;
}

// flag-tree grid barrier: relaxed atomics only; ordering via vmcnt drain + s_barrier
__device__ __forceinline__ void wsBarrier(unsigned* bar, int g, int tid, unsigned bgen) {
  asm volatile("s_waitcnt vmcnt(0)" ::: "memory");
  __syncthreads();
  if (g == LEADER) {
    if (tid < NWG) {
      while (ldAu(&bar[tid]) < bgen) __builtin_amdgcn_s_sleep(1);
    }
    __syncthreads();
    if (tid == 0) stAu(&bar[132], bgen);
  } else {
    if (tid == 0) {
      stAu(&bar[g], bgen);
      while (ldAu(&bar[132]) < bgen) __builtin_amdgcn_s_sleep(1);
    }
    __syncthreads();
  }
  asm volatile("" ::: "memory");
}

// block reduce over 512 threads (8 waves); returns sum to ALL threads
__device__ __forceinline__ float brs(float v, float* s8, int tid) {
  for (int o = 32; o > 0; o >>= 1) v += __shfl_down(v, o, 64);
  __syncthreads();                 // protect back-to-back s8 reuse
  if ((tid & 63) == 0) s8[tid >> 6] = v;
  __syncthreads();
  return s8[0]+s8[1]+s8[2]+s8[3]+s8[4]+s8[5]+s8[6]+s8[7];
}

__global__ __launch_bounds__(TPB)
void toyac_kernel(KParams p) {
  const int g = blockIdx.x;
  const int tid = threadIdx.x;
  const int c0 = ROWS * g;          // this worker's 4 memory rows
  float* ws = p.ws;
  unsigned* bar = (unsigned*)p.ws;

  __shared__ float sX[ROWS][EE];    // current rows (memPE) / new rows
  __shared__ float sP[ROWS][EE];    // bulk weighted sums
  __shared__ float sEv[ROWS][MM];   // exp scores per col
  __shared__ float sBuf[8192];      // 32KB scratch for partial reduces
  __shared__ float sH4[ROWS][HSS];  // writer hidden (4 rows)
  __shared__ float sHms[HSS];
  __shared__ float sRed[1024];      // minmax etc
  __shared__ float s8[8];
  __shared__ float sMS[EE];
  __shared__ float sMS2[EE];
  __shared__ float sSE[EE];
  __shared__ float sP1[HPP];
  __shared__ float sHv[HSS];
  __shared__ float sD[ROWS];
  __shared__ float sSm[32];

  unsigned bgen = 0;
  const int hq = (tid & 127) * 4;   // h-quad for [*,512] passes
  const int eg4 = tid >> 7;         // e-group (4 groups of 32)

  // ================= P0a =================
  if (g < NWG) {
    const int e = tid & 127, r = tid >> 7, c = c0 + r;
    double dv = exp(-(double)(2*(e>>1)) * log(10000.0) / 128.0);
    double arg = (double)c * dv;
    float pev = ((e & 1) == 0) ? (float)sin(arg) : (float)cos(arg);
    ws[OFF_PE + (size_t)c*EE + e] = pev;
    float m0v = p.mem0[(size_t)c*EE + e] + pev;
    stA(ws + OFF_MP + (size_t)c*EE + e, m0v);
    sX[r][e] = m0v;
  } else {
    // leader: composed matrices (leader-local)
    for (int jj = tid; jj < HSS; jj += TPB) {
      float a0=0.f,a1=0.f,a2=0.f,a3=0.f,cb=0.f;
      for (int e = 0; e < EE; ++e) {
        float wv = p.Ws[(size_t)e*HSS + jj];
        a0 += p.Wemb[e]*wv; a1 += p.Wemb[EE+e]*wv;
        a2 += p.Wemb[2*EE+e]*wv; a3 += p.Wemb[3*EE+e]*wv;
        cb += p.bemb[e]*wv;
      }
      ws[OFF_CS + jj] = a0; ws[OFF_CS + HSS + jj] = a1;
      ws[OFF_CS + 2*HSS + jj] = a2; ws[OFF_CS + 3*HSS + jj] = a3;
      ws[OFF_CBS + jj] = cb;
    }
    if (tid < HPP) {
      int k = tid;
      float a0=0.f,a1=0.f,a2=0.f,a3=0.f,cb=0.f;
      for (int e = 0; e < EE; ++e) {
        float wv = p.Wp1[(size_t)e*HPP + k];
        a0 += p.Wemb[e]*wv; a1 += p.Wemb[EE+e]*wv;
        a2 += p.Wemb[2*EE+e]*wv; a3 += p.Wemb[3*EE+e]*wv;
        cb += p.bemb[e]*wv;
      }
      ws[OFF_CP + k] = a0; ws[OFF_CP + HPP + k] = a1;
      ws[OFF_CP + 2*HPP + k] = a2; ws[OFF_CP + 3*HPP + k] = a3;
      ws[OFF_CBP + k] = cb;
    }
  }

  // ================= P0b: per-step R0 and W0 (input-only precompute) =================
  for (int t = g; t < BSZ; t += NWGT) {
    __syncthreads();
    if (tid < EE) {
      const float* st = p.state + (size_t)t*4;
      sSE[tid] = st[0]*p.Wemb[tid] + st[1]*p.Wemb[EE+tid]
               + st[2]*p.Wemb[2*EE+tid] + st[3]*p.Wemb[3*EE+tid] + p.bemb[tid];
    }
    __syncthreads();
    { // reader score r0: hidden partial via dwordx4 along h
      f4 a = {0.f,0.f,0.f,0.f};
      const float* base = p.Wr1 + (size_t)(eg4*32)*HSS + hq;
      for (int i = 0; i < 32; ++i)
        a += sSE[eg4*32 + i] * (*(const f4*)(base + (size_t)i*HSS));
      *(f4*)(sBuf + (size_t)eg4*HSS + hq) = a;
      __syncthreads();
      int h = tid;
      float hid = sBuf[h] + sBuf[HSS+h] + sBuf[2*HSS+h] + sBuf[3*HSS+h] + p.br1[h];
      float v = fmaxf(hid, 0.f) * p.Wr2[h];
      float sc = brs(v, s8, tid);
      if (tid == 0) stA(ws + OFF_R0 + t, sc + p.br2[0]);
      __syncthreads();
    }
    { // writer row0: hidden then full score row
      f4 a = {0.f,0.f,0.f,0.f};
      const float* base = p.Ww1 + (size_t)(eg4*32)*HSS + hq;
      for (int i = 0; i < 32; ++i)
        a += sSE[eg4*32 + i] * (*(const f4*)(base + (size_t)i*HSS));
      *(f4*)(sBuf + (size_t)eg4*HSS + hq) = a;
      __syncthreads();
      int h = tid;
      sHv[h] = fmaxf(sBuf[h] + sBuf[HSS+h] + sBuf[2*HSS+h] + sBuf[3*HSS+h] + p.bw1[h], 0.f);
      __syncthreads();
      const int cq = (tid & 63) * 4, hg = tid >> 6;   // 8 h-groups of 64
      f4 q = {0.f,0.f,0.f,0.f};
      const float* b2 = p.Ww2 + (size_t)(hg*64)*MM + cq;
      for (int i = 0; i < 64; ++i)
        q += sHv[hg*64 + i] * (*(const f4*)(b2 + (size_t)i*MM));
      *(f4*)(sBuf + (size_t)hg*MM + cq) = q;
      __syncthreads();
      if (tid < MM) {
        float s = 0.f;
        #pragma unroll
        for (int k = 0; k < 8; ++k) s += sBuf[(size_t)k*MM + tid];
        stA(ws + OFF_W0 + (size_t)t*MM + tid, s + p.bw2[tid]);
      }
      __syncthreads();
    }
  }

  // ================= stageAC lambda-equivalent (macro via function scope) ===========
  // implemented inline twice (prologue + loop) via a local auto lambda
  auto stageAC = [&](float* swdst) {
    // ---- reader hidden (4 rows) via dwordx4
    {
      f4 a0={0.f,0.f,0.f,0.f},a1=a0,a2=a0,a3=a0;
      const float* base = p.Wr1 + (size_t)(eg4*32)*HSS + hq;
      for (int i = 0; i < 32; ++i) {
        f4 w = *(const f4*)(base + (size_t)i*HSS);
        int e = eg4*32 + i;
        a0 += sX[0][e]*w; a1 += sX[1][e]*w; a2 += sX[2][e]*w; a3 += sX[3][e]*w;
      }
      *(f4*)(sBuf + ((size_t)eg4*ROWS + 0)*HSS + hq) = a0;
      *(f4*)(sBuf + ((size_t)eg4*ROWS + 1)*HSS + hq) = a1;
      *(f4*)(sBuf + ((size_t)eg4*ROWS + 2)*HSS + hq) = a2;
      *(f4*)(sBuf + ((size_t)eg4*ROWS + 3)*HSS + hq) = a3;
    }
    __syncthreads();
    float es[ROWS];
    {
      int h = tid;
      float b = p.br1[h], wr = p.Wr2[h];
      float sc[ROWS];
      #pragma unroll
      for (int r = 0; r < ROWS; ++r) {
        float hid = sBuf[(0*ROWS+r)*HSS+h] + sBuf[(1*ROWS+r)*HSS+h]
                  + sBuf[(2*ROWS+r)*HSS+h] + sBuf[(3*ROWS+r)*HSS+h] + b;
        sc[r] = fmaxf(hid, 0.f) * wr;
      }
      #pragma unroll
      for (int r = 0; r < ROWS; ++r) es[r] = expf(brs(sc[r], s8, tid) + p.br2[0]);
    }
    __syncthreads();
    if (tid < EE) {
      float v = es[0]*sX[0][tid] + es[1]*sX[1][tid] + es[2]*sX[2][tid] + es[3]*sX[3][tid];
      stA(ws + OFF_EV + (size_t)g*EE + tid, v);
    }
    if (tid == 0) stA(ws + OFF_ES + g, es[0]+es[1]+es[2]+es[3]);
    // ---- writer hidden (4 rows)
    {
      f4 a0={0.f,0.f,0.f,0.f},a1=a0,a2=a0,a3=a0;
      const float* base = p.Ww1 + (size_t)(eg4*32)*HSS + hq;
      for (int i = 0; i < 32; ++i) {
        f4 w = *(const f4*)(base + (size_t)i*HSS);
        int e = eg4*32 + i;
        a0 += sX[0][e]*w; a1 += sX[1][e]*w; a2 += sX[2][e]*w; a3 += sX[3][e]*w;
      }
      *(f4*)(sBuf + ((size_t)eg4*ROWS + 0)*HSS + hq) = a0;
      *(f4*)(sBuf + ((size_t)eg4*ROWS + 1)*HSS + hq) = a1;
      *(f4*)(sBuf + ((size_t)eg4*ROWS + 2)*HSS + hq) = a2;
      *(f4*)(sBuf + ((size_t)eg4*ROWS + 3)*HSS + hq) = a3;
    }
    __syncthreads();
    {
      int h = tid;
      float b = p.bw1[h];
      #pragma unroll
      for (int r = 0; r < ROWS; ++r)
        sH4[r][h] = fmaxf(sBuf[(0*ROWS+r)*HSS+h] + sBuf[(1*ROWS+r)*HSS+h]
                        + sBuf[(2*ROWS+r)*HSS+h] + sBuf[(3*ROWS+r)*HSS+h] + b, 0.f);
    }
    __syncthreads();
    // ---- writer score rows: [4x512]@[512x256] via dwordx4 along cols
    {
      const int cq = (tid & 63) * 4, hg = tid >> 6;
      f4 q0={0.f,0.f,0.f,0.f},q1=q0,q2=q0,q3=q0;
      const float* b2 = p.Ww2 + (size_t)(hg*64)*MM + cq;
      for (int i = 0; i < 64; ++i) {
        f4 w = *(const f4*)(b2 + (size_t)i*MM);
        int h = hg*64 + i;
        q0 += sH4[0][h]*w; q1 += sH4[1][h]*w; q2 += sH4[2][h]*w; q3 += sH4[3][h]*w;
      }
      *(f4*)(sBuf + ((size_t)hg*ROWS + 0)*MM + cq) = q0;
      *(f4*)(sBuf + ((size_t)hg*ROWS + 1)*MM + cq) = q1;
      *(f4*)(sBuf + ((size_t)hg*ROWS + 2)*MM + cq) = q2;
      *(f4*)(sBuf + ((size_t)hg*ROWS + 3)*MM + cq) = q3;
    }
    __syncthreads();
    {
      const int col = tid & 255, rp = tid >> 8;   // rp in {0,1} -> rows {2rp, 2rp+1}
      #pragma unroll
      for (int rr = 0; rr < 2; ++rr) {
        int r = rp*2 + rr;
        float s = 0.f;
        #pragma unroll
        for (int k = 0; k < 8; ++k) s += sBuf[((size_t)k*ROWS + r)*MM + col];
        stA(swdst + (size_t)(c0 + r)*MM + col, s + p.bw2[col]);
      }
    }
    __syncthreads();
  };

  // prologue: scores + reader partials for step 0
  if (g < NWG) {
    __syncthreads();
    stageAC(ws + OFF_SW);
  }
  wsBarrier(bar, g, tid, ++bgen);

  // ================= main sequential loop =================
  for (int t = 0; t < BSZ; ++t) {
    if (g == LEADER) {
      // ---------- leader phase 1 ----------
      const float* st = p.state + (size_t)t*4;
      const float s0 = st[0], s1 = st[1], s2 = st[2], s3 = st[3];
      if (tid < EE)
        sSE[tid] = s0*p.Wemb[tid] + s1*p.Wemb[EE+tid]
                 + s2*p.Wemb[2*EE+tid] + s3*p.Wemb[3*EE+tid] + p.bemb[tid];
      float er0 = expf(ldA(ws + OFF_R0 + t));
      float v = (tid < NWG) ? ldA(ws + OFF_ES + tid) : 0.f;
      float invd = 1.f / (er0 + brs(v, s8, tid));
      { // EV reduce: 64 vectors of 128; thread=(e4, qg of 4 q's)
        const int e4 = (tid & 31) * 4, qg = tid >> 5;  // 16 groups x 4 q
        f4 vv[4];
        ldA4x4(ws + OFF_EV + (size_t)(qg*4)*EE + e4, EE, vv);
        f4 acc = vv[0]+vv[1]+vv[2]+vv[3];
        *(f4*)(sBuf + (size_t)qg*EE + e4) = acc;
      }
      __syncthreads();
      if (tid < EE) {
        float s = 0.f;
        #pragma unroll
        for (int q = 0; q < 16; ++q) s += sBuf[(size_t)q*EE + tid];
        sMS[tid] = (er0*sSE[tid] + s) * invd;
      }
      __syncthreads();
      { // trunk hidden: mem_state half of Ws + composed state half
        f4 a = {0.f,0.f,0.f,0.f};
        const float* base = p.Ws + (size_t)(EE + eg4*32)*HSS + hq;
        for (int i = 0; i < 32; ++i)
          a += sMS[eg4*32 + i] * (*(const f4*)(base + (size_t)i*HSS));
        *(f4*)(sBuf + (size_t)eg4*HSS + hq) = a;
      }
      __syncthreads();
      {
        int j = tid;
        const float* cs = ws + OFF_CS;
        float sh0 = s0*cs[j] + s1*cs[HSS+j] + s2*cs[2*HSS+j] + s3*cs[3*HSS+j] + ws[OFF_CBS + j];
        float hv = sBuf[j] + sBuf[HSS+j] + sBuf[2*HSS+j] + sBuf[3*HSS+j] + sh0 + p.bs[j];
        sHv[j] = fmaxf(hv, 0.f);
      }
      __syncthreads();
      { // actor/critic
        int j = tid;
        float hv = sHv[j];
        float pa[6];
        #pragma unroll
        for (int aa = 0; aa < 5; ++aa) pa[aa] = hv * p.Wa[(size_t)j*5 + aa];
        pa[5] = hv * p.Wc[j];
        #pragma unroll
        for (int aa = 0; aa < 6; ++aa) {
          float r = brs(pa[aa], s8, tid);
          if (tid == 0) sSm[1+aa] = r;
        }
        __syncthreads();
        if (tid == 0) {
          float l0=sSm[1]+p.ba[0], l1=sSm[2]+p.ba[1], l2=sSm[3]+p.ba[2];
          float l3=sSm[4]+p.ba[3], l4=sSm[5]+p.ba[4];
          float mx = fmaxf(fmaxf(fmaxf(l0,l1),fmaxf(l2,l3)), l4);
          float e0=expf(l0-mx),e1=expf(l1-mx),e2=expf(l2-mx),e3=expf(l3-mx),e4v=expf(l4-mx);
          float is = 1.f/(e0+e1+e2+e3+e4v);
          float p0=e0*is,p1=e1*is,p2=e2*is,p3=e3*is,p4=e4v*is;
          p.out[(size_t)t*5+0]=p0; p.out[(size_t)t*5+1]=p1; p.out[(size_t)t*5+2]=p2;
          p.out[(size_t)t*5+3]=p3; p.out[(size_t)t*5+4]=p4;
          float val = sSm[6] + p.bc[0];
          p.out[(size_t)BSZ*5 + t] = val;
          sSm[1]=p0; sSm[2]=p1; sSm[3]=p2; sSm[4]=p3; sSm[5]=p4; sSm[6]=val;
        }
        __syncthreads();
      }
      { // p1 = relu(pin @ Wp1 + bp1): mem_state half via dwordx4
        const int cq = (tid & 63) * 4, eg8 = tid >> 6;  // 8 e-groups of 16
        f4 a = {0.f,0.f,0.f,0.f};
        const float* base = p.Wp1 + (size_t)(EE + eg8*16)*HPP + cq;
        for (int i = 0; i < 16; ++i)
          a += sMS[eg8*16 + i] * (*(const f4*)(base + (size_t)i*HPP));
        *(f4*)(sBuf + (size_t)eg8*HPP + cq) = a;
      }
      __syncthreads();
      if (tid < HPP) {
        int k = tid;
        const float* cp = ws + OFF_CP;
        float acc = s0*cp[k] + s1*cp[HPP+k] + s2*cp[2*HPP+k] + s3*cp[3*HPP+k]
                  + ws[OFF_CBP + k] + p.bp1[k];
        #pragma unroll
        for (int q = 0; q < 8; ++q) acc += sBuf[(size_t)q*HPP + k];
        #pragma unroll
        for (int aa = 0; aa < 5; ++aa) acc += sSm[1+aa] * p.Wp1[(size_t)(2*EE+aa)*HPP + k];
        acc += sSm[6] * p.Wp1[(size_t)(2*EE+5)*HPP + k];
        sP1[k] = fmaxf(acc, 0.f);
      }
      __syncthreads();
      { // ms2 = p1 @ Wp2 + bp2
        const int cq = (tid & 31) * 4, kg = tid >> 5;  // 16 k-groups of 16
        f4 a = {0.f,0.f,0.f,0.f};
        const float* base = p.Wp2 + (size_t)(kg*16)*EE + cq;
        for (int i = 0; i < 16; ++i)
          a += sP1[kg*16 + i] * (*(const f4*)(base + (size_t)i*EE));
        *(f4*)(sBuf + (size_t)kg*EE + cq) = a;
      }
      __syncthreads();
      if (tid < EE) {
        float s = 0.f;
        #pragma unroll
        for (int q = 0; q < 16; ++q) s += sBuf[(size_t)q*EE + tid];
        float m = s + p.bp2[tid];
        sMS[tid] = m;
        stA(ws + OFF_MS2 + tid, m);
      }
      __syncthreads();
      { // hms = relu(ms2 @ Ww1 + bw1)
        f4 a = {0.f,0.f,0.f,0.f};
        const float* base = p.Ww1 + (size_t)(eg4*32)*HSS + hq;
        for (int i = 0; i < 32; ++i)
          a += sMS[eg4*32 + i] * (*(const f4*)(base + (size_t)i*HSS));
        *(f4*)(sBuf + (size_t)eg4*HSS + hq) = a;
      }
      __syncthreads();
      {
        int h = tid;
        stA(ws + OFF_HMS + h,
            fmaxf(sBuf[h] + sBuf[HSS+h] + sBuf[2*HSS+h] + sBuf[3*HSS+h] + p.bw1[h], 0.f));
      }
    } else {
      // ---------- worker phase 1: dBulk ----------
      float* swc = ws + OFF_SW + (size_t)(t&1)*MM*MM;
      float* mpc = ws + OFF_MP + (size_t)(t&1)*MM*EE;
      float ex[ROWS] = {0.f,0.f,0.f,0.f};
      if (tid < MM) {
        f4 s = ldA4(swc + (size_t)tid*MM + c0);
        #pragma unroll
        for (int r = 0; r < ROWS; ++r) { ex[r] = expf(s[r]); sEv[r][tid] = ex[r]; }
      }
      #pragma unroll
      for (int r = 0; r < ROWS; ++r) {
        float d = brs(ex[r], s8, tid);
        if (tid == 0) sD[r] = d;
      }
      __syncthreads();
      { // weighted sums: thread=(e4, rg of 16 rows)
        const int e4 = (tid & 31) * 4, rg = tid >> 5;  // 16 groups x 16 rows
        f4 a0={0.f,0.f,0.f,0.f},a1=a0,a2=a0,a3=a0;
        const float* base = mpc + (size_t)(rg*16)*EE + e4;
        f4 vv[8];
        ldA4x8(base, EE, vv);
        #pragma unroll
        for (int i = 0; i < 8; ++i) {
          int r0 = rg*16 + i;
          a0 += sEv[0][r0]*vv[i]; a1 += sEv[1][r0]*vv[i];
          a2 += sEv[2][r0]*vv[i]; a3 += sEv[3][r0]*vv[i];
        }
        ldA4x8(base + 8*EE, EE, vv);
        #pragma unroll
        for (int i = 0; i < 8; ++i) {
          int r0 = rg*16 + 8 + i;
          a0 += sEv[0][r0]*vv[i]; a1 += sEv[1][r0]*vv[i];
          a2 += sEv[2][r0]*vv[i]; a3 += sEv[3][r0]*vv[i];
        }
        *(f4*)(sBuf + ((size_t)0*16 + rg)*EE + e4) = a0;
        *(f4*)(sBuf + ((size_t)1*16 + rg)*EE + e4) = a1;
        *(f4*)(sBuf + ((size_t)2*16 + rg)*EE + e4) = a2;
        *(f4*)(sBuf + ((size_t)3*16 + rg)*EE + e4) = a3;
      }
      __syncthreads();
      {
        const int e = tid & 127, r = tid >> 7;
        float s = 0.f;
        #pragma unroll
        for (int q = 0; q < 16; ++q) s += sBuf[((size_t)r*16 + q)*EE + e];
        sP[r][e] = s;
      }
      __syncthreads();
    }
    wsBarrier(bar, g, tid, ++bgen);
    if (g < NWG && t < BSZ - 1) {
      // ---------- worker phase 2: dFinish + stageAC ----------
      if (tid < EE) sMS2[tid] = ldA(ws + OFF_MS2 + tid);
      sHms[tid] = ldA(ws + OFF_HMS + tid);
      if (tid == 0) {
        f4 w0 = ldA4(ws + OFF_W0 + (size_t)t*MM + c0);
        #pragma unroll
        for (int r = 0; r < ROWS; ++r) sSm[8+r] = expf(w0[r]);
      }
      __syncthreads();
      { // writer row-1 scores for own 4 cols
        f4 w = *(const f4*)(p.Ww2 + (size_t)tid*MM + c0);
        float hm = sHms[tid];
        float sw1[ROWS];
        #pragma unroll
        for (int r = 0; r < ROWS; ++r) sw1[r] = brs(hm * w[r], s8, tid);
        float ew1[ROWS], ew0[ROWS], inv[ROWS];
        #pragma unroll
        for (int r = 0; r < ROWS; ++r) {
          ew1[r] = expf(sw1[r] + p.bw2[c0+r]);
          ew0[r] = sSm[8+r];
          inv[r] = 1.f / (sD[r] + ew0[r] + ew1[r]);
        }
        const int e = tid & 127, r = tid >> 7;   // covers rows 0..3? no: tid>>7 in 0..3 for 512 threads
        const float* st = p.state + (size_t)t*4;
        float se = st[0]*p.Wemb[e] + st[1]*p.Wemb[EE+e]
                 + st[2]*p.Wemb[2*EE+e] + st[3]*p.Wemb[3*EE+e] + p.bemb[e];
        float x = (sP[r][e] + ew0[r]*se + ew1[r]*sMS2[e]) * inv[r];
        sRed[(size_t)r*EE + e] = x;          // min tree
        sRed[512 + (size_t)r*EE + e] = x;    // max tree
        sX[r][e] = x;
      }
      __syncthreads();
      for (int s = 64; s > 0; s >>= 1) {
        const int e = tid & 127, r = tid >> 7;
        if (e < s) {
          sRed[(size_t)r*EE + e] = fminf(sRed[(size_t)r*EE + e], sRed[(size_t)r*EE + e + s]);
          sRed[512 + (size_t)r*EE + e] = fmaxf(sRed[512 + (size_t)r*EE + e], sRed[512 + (size_t)r*EE + e + s]);
        }
        __syncthreads();
      }
      {
        const int e = tid & 127, r = tid >> 7;
        float mn = sRed[(size_t)r*EE], mx = sRed[512 + (size_t)r*EE];
        float x = (sX[r][e] - mn) / (mx - mn) + ws[OFF_PE + (size_t)(c0+r)*EE + e];
        float* mpn = ws + OFF_MP + (size_t)((t+1)&1)*MM*EE;
        stA(mpn + (size_t)(c0+r)*EE + e, x);
        __syncthreads();
        sX[r][e] = x;
      }
      __syncthreads();
      stageAC(ws + OFF_SW + (size_t)((t+1)&1)*MM*MM);
    }
    wsBarrier(bar, g, tid, ++bgen);
  }
}

extern "C" void kernel_launch(void* const* d_in, const int* in_sizes, int n_in,
                              void* d_out, int out_size, void* d_ws, size_t ws_size,
                              hipStream_t stream) {
  hipMemsetAsync(d_ws, 0, 2048, stream);  // barrier flags/release
  KParams kp;
  kp.state = (const float*)d_in[0];
  kp.mem0  = (const float*)d_in[1];
  kp.Wemb  = (const float*)d_in[2];
  kp.bemb  = (const float*)d_in[3];
  kp.Wr1   = (const float*)d_in[4];
  kp.br1   = (const float*)d_in[5];
  kp.Wr2   = (const float*)d_in[6];
  kp.br2   = (const float*)d_in[7];
  kp.Ww1   = (const float*)d_in[8];
  kp.bw1   = (const float*)d_in[9];
  kp.Ww2   = (const float*)d_in[10];
  kp.bw2   = (const float*)d_in[11];
  kp.Ws    = (const float*)d_in[12];
  kp.bs    = (const float*)d_in[13];
  kp.Wa    = (const float*)d_in[14];
  kp.ba    = (const float*)d_in[15];
  kp.Wc    = (const float*)d_in[16];
  kp.bc    = (const float*)d_in[17];
  kp.Wp1   = (const float*)d_in[18];
  kp.bp1   = (const float*)d_in[19];
  kp.Wp2   = (const float*)d_in[20];
  kp.bp2   = (const float*)d_in[21];
  kp.out   = (float*)d_out;
  kp.ws    = (float*)d_ws;
  toyac_kernel<<<dim3(NWGT), dim3(TPB), 0, stream>>>(kp);
}

// Round 6
// 63400.275 us; speedup vs baseline: 27.9456x; 1.6776x over previous
//
#include <hip/hip_runtime.h>
#include <math.h>

#define BSZ 2048   // batch steps
#define MM  256    // memory slots
#define EE  128    // embedding dim
#define HSS 512    // summarizer hidden
#define HPP 256    // processor hidden
#define NWG 64     // worker blocks (4 memory rows each)
#define NWGT 65    // workers + 1 leader
#define LEADER 64
#define TPB 512
#define ROWS 4

typedef float f4 __attribute__((ext_vector_type(4)));

// workspace offsets (floats). First 512 floats: flags (memset 0).
// bar[0..63]=flagA, bar[64..127]=flagC, bar[160]=leaderDone
#define OFF_PE   512
#define OFF_R0   (OFF_PE + MM*EE)
#define OFF_W0   (OFF_R0 + BSZ)
#define OFF_MP   (OFF_W0 + BSZ*MM)        // memPE double buffer: 2*MM*EE
#define OFF_SW   (OFF_MP + 2*MM*EE)       // writer scores ROW-MAJOR [buf][row][col]: 2*MM*MM
#define OFF_EV   (OFF_SW + 2*MM*MM)       // per-WG exp-weighted partials: NWG*EE
#define OFF_ES   (OFF_EV + NWG*EE)        // per-WG exp sums: NWG
#define OFF_MS2  (OFF_ES + NWG)           // ms2: EE
#define OFF_HMS  (OFF_MS2 + EE)           // relu(ms2@Ww1+bw1): HSS
#define OFF_CS   (OFF_HMS + HSS)          // Wemb@Ws[0:128,:]: 4*HSS (leader-local)
#define OFF_CBS  (OFF_CS + 4*HSS)
#define OFF_CP   (OFF_CBS + HSS)          // Wemb@Wp1[0:128,:]: 4*HPP
#define OFF_CBP  (OFF_CP + 4*HPP)

struct KParams {
  const float *state, *mem0, *Wemb, *bemb, *Wr1, *br1, *Wr2, *br2;
  const float *Ww1, *bw1, *Ww2, *bw2, *Ws, *bs, *Wa, *ba, *Wc, *bc;
  const float *Wp1, *bp1, *Wp2, *bp2;
  float *out;
  float *ws;
};

// ---- relaxed agent-scope ops (coherent across XCDs, no cache maintenance) ----
__device__ __forceinline__ float ldA(const float* p) {
  return __hip_atomic_load(p, __ATOMIC_RELAXED, __HIP_MEMORY_SCOPE_AGENT);
}
__device__ __forceinline__ void stA(float* p, float v) {
  __hip_atomic_store(p, v, __ATOMIC_RELAXED, __HIP_MEMORY_SCOPE_AGENT);
}
__device__ __forceinline__ unsigned ldAu(const unsigned* p) {
  return __hip_atomic_load(p, __ATOMIC_RELAXED, __HIP_MEMORY_SCOPE_AGENT);
}
__device__ __forceinline__ void stAu(unsigned* p, unsigned v) {
  __hip_atomic_store(p, v, __ATOMIC_RELAXED, __HIP_MEMORY_SCOPE_AGENT);
}

// ---- batched L2-bypass vector loads: N independent dwordx4, ONE waitcnt ----
__device__ __forceinline__ void ldA4x8(const float* p, int strideF, f4* v) {
  const float *p1=p+strideF, *p2=p+2*strideF, *p3=p+3*strideF,
              *p4=p+4*strideF, *p5=p+5*strideF, *p6=p+6*strideF, *p7=p+7*strideF;
  asm volatile(
    "global_load_dwordx4 %0, %8, off sc0 sc1\n\t"
    "global_load_dwordx4 %1, %9, off sc0 sc1\n\t"
    "global_load_dwordx4 %2, %10, off sc0 sc1\n\t"
    "global_load_dwordx4 %3, %11, off sc0 sc1\n\t"
    "global_load_dwordx4 %4, %12, off sc0 sc1\n\t"
    "global_load_dwordx4 %5, %13, off sc0 sc1\n\t"
    "global_load_dwordx4 %6, %14, off sc0 sc1\n\t"
    "global_load_dwordx4 %7, %15, off sc0 sc1\n\t"
    "s_waitcnt vmcnt(0)"
    : "=&v"(v[0]), "=&v"(v[1]), "=&v"(v[2]), "=&v"(v[3]),
      "=&v"(v[4]), "=&v"(v[5]), "=&v"(v[6]), "=&v"(v[7])
    : "v"(p), "v"(p1), "v"(p2), "v"(p3), "v"(p4), "v"(p5), "v"(p6), "v"(p7)
    : "memory");
}
__device__ __forceinline__ void ldA4x4(const float* p, int strideF, f4* v) {
  const float *p1=p+strideF, *p2=p+2*strideF, *p3=p+3*strideF;
  asm volatile(
    "global_load_dwordx4 %0, %4, off sc0 sc1\n\t"
    "global_load_dwordx4 %1, %5, off sc0 sc1\n\t"
    "global_load_dwordx4 %2, %6, off sc0 sc1\n\t"
    "global_load_dwordx4 %3, %7, off sc0 sc1\n\t"
    "s_waitcnt vmcnt(0)"
    : "=&v"(v[0]), "=&v"(v[1]), "=&v"(v[2]), "=&v"(v[3])
    : "v"(p), "v"(p1), "v"(p2), "v"(p3)
    : "memory");
}
__device__ __forceinline__ f4 ldA4(const float* p) {
  f4 r;
  asm volatile("global_load_dwordx4 %0, %1, off sc0 sc1\n\ts_waitcnt vmcnt(0)"
    : "=&v"(r) : "v"(p) : "memory");
  return r;
}

// all waves drain their stores, then block sync (before setting a flag)
__device__ __forceinline__ void drainSync() {
  asm volatile("s_waitcnt vmcnt(0)" ::: "memory");
  __syncthreads();
}

// block reduce over 512 threads; returns sum to ALL threads (single value)
__device__ __forceinline__ float brs(float v, float* s8, int tid) {
  for (int o = 32; o > 0; o >>= 1) v += __shfl_down(v, o, 64);
  __syncthreads();
  if ((tid & 63) == 0) s8[tid >> 6] = v;
  __syncthreads();
  float r = s8[0]+s8[1]+s8[2]+s8[3]+s8[4]+s8[5]+s8[6]+s8[7];
  __syncthreads();
  return r;
}

// batched block reduce: N sums at once, identical per-value arithmetic to brs
template<int N>
__device__ __forceinline__ void brsN(float* v, float* sred, int tid) {
  #pragma unroll
  for (int k = 0; k < N; ++k)
    for (int o = 32; o > 0; o >>= 1) v[k] += __shfl_down(v[k], o, 64);
  __syncthreads();
  if ((tid & 63) == 0) {
    const int w = tid >> 6;
    #pragma unroll
    for (int k = 0; k < N; ++k) sred[k*8 + w] = v[k];
  }
  __syncthreads();
  #pragma unroll
  for (int k = 0; k < N; ++k) {
    float s = sred[k*8 + 0];
    #pragma unroll
    for (int w = 1; w < 8; ++w) s += sred[k*8 + w];
    v[k] = s;
  }
  __syncthreads();
}

__global__ __launch_bounds__(TPB)
void toyac_kernel(KParams p) {
  const int g = blockIdx.x;
  const int tid = threadIdx.x;
  const int c0 = ROWS * g;
  float* ws = p.ws;
  unsigned* bar = (unsigned*)p.ws;

  __shared__ float sX[ROWS][EE];
  __shared__ float sP[ROWS][EE];
  __shared__ float sEv[ROWS][MM];
  __shared__ float sBuf[8192];
  __shared__ float sH4[ROWS][HSS];
  __shared__ float sHms[HSS];
  __shared__ float sRed[1024];
  __shared__ float s8[8];
  __shared__ float sR48[48];
  __shared__ float sMS[EE];
  __shared__ float sMS2[EE];
  __shared__ float sSE[EE];
  __shared__ float sP1[HPP];
  __shared__ float sHv[HSS];
  __shared__ float sD[ROWS];
  __shared__ float sSm[32];

  const int hq = (tid & 127) * 4;
  const int eg4 = tid >> 7;

  // ================= P0a =================
  if (g < NWG) {
    const int e = tid & 127, r = tid >> 7, c = c0 + r;
    double dv = exp(-(double)(2*(e>>1)) * log(10000.0) / 128.0);
    double arg = (double)c * dv;
    float pev = ((e & 1) == 0) ? (float)sin(arg) : (float)cos(arg);
    ws[OFF_PE + (size_t)c*EE + e] = pev;
    float m0v = p.mem0[(size_t)c*EE + e] + pev;
    stA(ws + OFF_MP + (size_t)c*EE + e, m0v);
    sX[r][e] = m0v;
  } else {
    for (int jj = tid; jj < HSS; jj += TPB) {
      float a0=0.f,a1=0.f,a2=0.f,a3=0.f,cb=0.f;
      for (int e = 0; e < EE; ++e) {
        float wv = p.Ws[(size_t)e*HSS + jj];
        a0 += p.Wemb[e]*wv; a1 += p.Wemb[EE+e]*wv;
        a2 += p.Wemb[2*EE+e]*wv; a3 += p.Wemb[3*EE+e]*wv;
        cb += p.bemb[e]*wv;
      }
      ws[OFF_CS + jj] = a0; ws[OFF_CS + HSS + jj] = a1;
      ws[OFF_CS + 2*HSS + jj] = a2; ws[OFF_CS + 3*HSS + jj] = a3;
      ws[OFF_CBS + jj] = cb;
    }
    if (tid < HPP) {
      int k = tid;
      float a0=0.f,a1=0.f,a2=0.f,a3=0.f,cb=0.f;
      for (int e = 0; e < EE; ++e) {
        float wv = p.Wp1[(size_t)e*HPP + k];
        a0 += p.Wemb[e]*wv; a1 += p.Wemb[EE+e]*wv;
        a2 += p.Wemb[2*EE+e]*wv; a3 += p.Wemb[3*EE+e]*wv;
        cb += p.bemb[e]*wv;
      }
      ws[OFF_CP + k] = a0; ws[OFF_CP + HPP + k] = a1;
      ws[OFF_CP + 2*HPP + k] = a2; ws[OFF_CP + 3*HPP + k] = a3;
      ws[OFF_CBP + k] = cb;
    }
  }

  // ================= P0b: per-step R0 and W0 =================
  for (int t = g; t < BSZ; t += NWGT) {
    __syncthreads();
    if (tid < EE) {
      const float* st = p.state + (size_t)t*4;
      sSE[tid] = st[0]*p.Wemb[tid] + st[1]*p.Wemb[EE+tid]
               + st[2]*p.Wemb[2*EE+tid] + st[3]*p.Wemb[3*EE+tid] + p.bemb[tid];
    }
    __syncthreads();
    { // reader score r0
      f4 a = {0.f,0.f,0.f,0.f};
      const float* base = p.Wr1 + (size_t)(eg4*32)*HSS + hq;
      for (int i = 0; i < 32; ++i)
        a += sSE[eg4*32 + i] * (*(const f4*)(base + (size_t)i*HSS));
      *(f4*)(sBuf + (size_t)eg4*HSS + hq) = a;
      __syncthreads();
      int h = tid;
      float hid = sBuf[h] + sBuf[HSS+h] + sBuf[2*HSS+h] + sBuf[3*HSS+h] + p.br1[h];
      float v = fmaxf(hid, 0.f) * p.Wr2[h];
      float sc = brs(v, s8, tid);
      if (tid == 0) stA(ws + OFF_R0 + t, sc + p.br2[0]);
      __syncthreads();
    }
    { // writer row0
      f4 a = {0.f,0.f,0.f,0.f};
      const float* base = p.Ww1 + (size_t)(eg4*32)*HSS + hq;
      for (int i = 0; i < 32; ++i)
        a += sSE[eg4*32 + i] * (*(const f4*)(base + (size_t)i*HSS));
      *(f4*)(sBuf + (size_t)eg4*HSS + hq) = a;
      __syncthreads();
      int h = tid;
      sHv[h] = fmaxf(sBuf[h] + sBuf[HSS+h] + sBuf[2*HSS+h] + sBuf[3*HSS+h] + p.bw1[h], 0.f);
      __syncthreads();
      const int cq = (tid & 63) * 4, hg = tid >> 6;
      f4 q = {0.f,0.f,0.f,0.f};
      const float* b2 = p.Ww2 + (size_t)(hg*64)*MM + cq;
      for (int i = 0; i < 64; ++i)
        q += sHv[hg*64 + i] * (*(const f4*)(b2 + (size_t)i*MM));
      *(f4*)(sBuf + (size_t)hg*MM + cq) = q;
      __syncthreads();
      if (tid < MM) {
        float s = 0.f;
        #pragma unroll
        for (int k = 0; k < 8; ++k) s += sBuf[(size_t)k*MM + tid];
        stA(ws + OFF_W0 + (size_t)t*MM + tid, s + p.bw2[tid]);
      }
      __syncthreads();
    }
  }

  // ================= worker lambdas =================
  auto stageA = [&]() {
    { // reader hidden (4 rows)
      f4 a0={0.f,0.f,0.f,0.f},a1=a0,a2=a0,a3=a0;
      const float* base = p.Wr1 + (size_t)(eg4*32)*HSS + hq;
      for (int i = 0; i < 32; ++i) {
        f4 w = *(const f4*)(base + (size_t)i*HSS);
        int e = eg4*32 + i;
        a0 += sX[0][e]*w; a1 += sX[1][e]*w; a2 += sX[2][e]*w; a3 += sX[3][e]*w;
      }
      *(f4*)(sBuf + ((size_t)eg4*ROWS + 0)*HSS + hq) = a0;
      *(f4*)(sBuf + ((size_t)eg4*ROWS + 1)*HSS + hq) = a1;
      *(f4*)(sBuf + ((size_t)eg4*ROWS + 2)*HSS + hq) = a2;
      *(f4*)(sBuf + ((size_t)eg4*ROWS + 3)*HSS + hq) = a3;
    }
    __syncthreads();
    float es[ROWS];
    {
      int h = tid;
      float b = p.br1[h], wr = p.Wr2[h];
      float sc[ROWS];
      #pragma unroll
      for (int r = 0; r < ROWS; ++r) {
        float hid = sBuf[(0*ROWS+r)*HSS+h] + sBuf[(1*ROWS+r)*HSS+h]
                  + sBuf[(2*ROWS+r)*HSS+h] + sBuf[(3*ROWS+r)*HSS+h] + b;
        sc[r] = fmaxf(hid, 0.f) * wr;
      }
      brsN<ROWS>(sc, sR48, tid);
      #pragma unroll
      for (int r = 0; r < ROWS; ++r) es[r] = expf(sc[r] + p.br2[0]);
    }
    if (tid < EE) {
      float v = es[0]*sX[0][tid] + es[1]*sX[1][tid] + es[2]*sX[2][tid] + es[3]*sX[3][tid];
      stA(ws + OFF_EV + (size_t)g*EE + tid, v);
    }
    if (tid == 0) stA(ws + OFF_ES + g, es[0]+es[1]+es[2]+es[3]);
  };

  auto stageC = [&](float* swdst) {
    { // writer hidden (4 rows)
      f4 a0={0.f,0.f,0.f,0.f},a1=a0,a2=a0,a3=a0;
      const float* base = p.Ww1 + (size_t)(eg4*32)*HSS + hq;
      for (int i = 0; i < 32; ++i) {
        f4 w = *(const f4*)(base + (size_t)i*HSS);
        int e = eg4*32 + i;
        a0 += sX[0][e]*w; a1 += sX[1][e]*w; a2 += sX[2][e]*w; a3 += sX[3][e]*w;
      }
      *(f4*)(sBuf + ((size_t)eg4*ROWS + 0)*HSS + hq) = a0;
      *(f4*)(sBuf + ((size_t)eg4*ROWS + 1)*HSS + hq) = a1;
      *(f4*)(sBuf + ((size_t)eg4*ROWS + 2)*HSS + hq) = a2;
      *(f4*)(sBuf + ((size_t)eg4*ROWS + 3)*HSS + hq) = a3;
    }
    __syncthreads();
    {
      int h = tid;
      float b = p.bw1[h];
      #pragma unroll
      for (int r = 0; r < ROWS; ++r)
        sH4[r][h] = fmaxf(sBuf[(0*ROWS+r)*HSS+h] + sBuf[(1*ROWS+r)*HSS+h]
                        + sBuf[(2*ROWS+r)*HSS+h] + sBuf[(3*ROWS+r)*HSS+h] + b, 0.f);
    }
    __syncthreads();
    {
      const int cq = (tid & 63) * 4, hg = tid >> 6;
      f4 q0={0.f,0.f,0.f,0.f},q1=q0,q2=q0,q3=q0;
      const float* b2 = p.Ww2 + (size_t)(hg*64)*MM + cq;
      for (int i = 0; i < 64; ++i) {
        f4 w = *(const f4*)(b2 + (size_t)i*MM);
        int h = hg*64 + i;
        q0 += sH4[0][h]*w; q1 += sH4[1][h]*w; q2 += sH4[2][h]*w; q3 += sH4[3][h]*w;
      }
      *(f4*)(sBuf + ((size_t)hg*ROWS + 0)*MM + cq) = q0;
      *(f4*)(sBuf + ((size_t)hg*ROWS + 1)*MM + cq) = q1;
      *(f4*)(sBuf + ((size_t)hg*ROWS + 2)*MM + cq) = q2;
      *(f4*)(sBuf + ((size_t)hg*ROWS + 3)*MM + cq) = q3;
    }
    __syncthreads();
    {
      const int col = tid & 255, rp = tid >> 8;
      #pragma unroll
      for (int rr = 0; rr < 2; ++rr) {
        int r = rp*2 + rr;
        float s = 0.f;
        #pragma unroll
        for (int k = 0; k < 8; ++k) s += sBuf[((size_t)k*ROWS + r)*MM + col];
        stA(swdst + (size_t)(c0 + r)*MM + col, s + p.bw2[col]);
      }
    }
    __syncthreads();
  };

  auto dBulk = [&](int t) {
    float* swc = ws + OFF_SW + (size_t)(t&1)*MM*MM;
    float* mpc = ws + OFF_MP + (size_t)(t&1)*MM*EE;
    float ex[ROWS] = {0.f,0.f,0.f,0.f};
    if (tid < MM) {
      f4 s = ldA4(swc + (size_t)tid*MM + c0);
      #pragma unroll
      for (int r = 0; r < ROWS; ++r) { ex[r] = expf(s[r]); sEv[r][tid] = ex[r]; }
    }
    brsN<ROWS>(ex, sR48, tid);
    if (tid == 0) { sD[0]=ex[0]; sD[1]=ex[1]; sD[2]=ex[2]; sD[3]=ex[3]; }
    __syncthreads();
    {
      const int e4 = (tid & 31) * 4, rg = tid >> 5;
      f4 a0={0.f,0.f,0.f,0.f},a1=a0,a2=a0,a3=a0;
      const float* base = mpc + (size_t)(rg*16)*EE + e4;
      f4 vv[8];
      ldA4x8(base, EE, vv);
      #pragma unroll
      for (int i = 0; i < 8; ++i) {
        int r0 = rg*16 + i;
        a0 += sEv[0][r0]*vv[i]; a1 += sEv[1][r0]*vv[i];
        a2 += sEv[2][r0]*vv[i]; a3 += sEv[3][r0]*vv[i];
      }
      ldA4x8(base + 8*EE, EE, vv);
      #pragma unroll
      for (int i = 0; i < 8; ++i) {
        int r0 = rg*16 + 8 + i;
        a0 += sEv[0][r0]*vv[i]; a1 += sEv[1][r0]*vv[i];
        a2 += sEv[2][r0]*vv[i]; a3 += sEv[3][r0]*vv[i];
      }
      *(f4*)(sBuf + ((size_t)0*16 + rg)*EE + e4) = a0;
      *(f4*)(sBuf + ((size_t)1*16 + rg)*EE + e4) = a1;
      *(f4*)(sBuf + ((size_t)2*16 + rg)*EE + e4) = a2;
      *(f4*)(sBuf + ((size_t)3*16 + rg)*EE + e4) = a3;
    }
    __syncthreads();
    {
      const int e = tid & 127, r = tid >> 7;
      float s = 0.f;
      #pragma unroll
      for (int q = 0; q < 16; ++q) s += sBuf[((size_t)r*16 + q)*EE + e];
      sP[r][e] = s;
    }
    __syncthreads();
  };

  auto dFinish = [&](int t) {
    if (tid < EE) sMS2[tid] = ldA(ws + OFF_MS2 + tid);
    sHms[tid] = ldA(ws + OFF_HMS + tid);
    if (tid == 0) {
      f4 w0 = ldA4(ws + OFF_W0 + (size_t)t*MM + c0);
      #pragma unroll
      for (int r = 0; r < ROWS; ++r) sSm[8+r] = expf(w0[r]);
    }
    __syncthreads();
    {
      f4 w = *(const f4*)(p.Ww2 + (size_t)tid*MM + c0);
      float hm = sHms[tid];
      float sw1[ROWS] = { hm*w[0], hm*w[1], hm*w[2], hm*w[3] };
      brsN<ROWS>(sw1, sR48, tid);
      float ew1[ROWS], ew0[ROWS], inv[ROWS];
      #pragma unroll
      for (int r = 0; r < ROWS; ++r) {
        ew1[r] = expf(sw1[r] + p.bw2[c0+r]);
        ew0[r] = sSm[8+r];
        inv[r] = 1.f / (sD[r] + ew0[r] + ew1[r]);
      }
      const int e = tid & 127, r = tid >> 7;
      const float* st = p.state + (size_t)t*4;
      float se = st[0]*p.Wemb[e] + st[1]*p.Wemb[EE+e]
               + st[2]*p.Wemb[2*EE+e] + st[3]*p.Wemb[3*EE+e] + p.bemb[e];
      float x = (sP[r][e] + ew0[r]*se + ew1[r]*sMS2[e]) * inv[r];
      sRed[(size_t)r*EE + e] = x;
      sRed[512 + (size_t)r*EE + e] = x;
      sX[r][e] = x;
    }
    __syncthreads();
    for (int s = 64; s > 0; s >>= 1) {
      const int e = tid & 127, r = tid >> 7;
      if (e < s) {
        sRed[(size_t)r*EE + e] = fminf(sRed[(size_t)r*EE + e], sRed[(size_t)r*EE + e + s]);
        sRed[512 + (size_t)r*EE + e] = fmaxf(sRed[512 + (size_t)r*EE + e], sRed[512 + (size_t)r*EE + e + s]);
      }
      __syncthreads();
    }
    {
      const int e = tid & 127, r = tid >> 7;
      float mn = sRed[(size_t)r*EE], mx = sRed[512 + (size_t)r*EE];
      float x = (sX[r][e] - mn) / (mx - mn) + ws[OFF_PE + (size_t)(c0+r)*EE + e];
      float* mpn = ws + OFF_MP + (size_t)((t+1)&1)*MM*EE;
      stA(mpn + (size_t)(c0+r)*EE + e, x);
      __syncthreads();
      sX[r][e] = x;
    }
    __syncthreads();
  };

  // ================= main =================
  if (g == LEADER) {
    for (int t = 0; t < BSZ; ++t) {
      // wait for EV/ES(t)
      if (tid < NWG) {
        while (ldAu(&bar[tid]) < (unsigned)(t+1)) __builtin_amdgcn_s_sleep(1);
      }
      __syncthreads();
      // ---------- leader chain ----------
      const float* st = p.state + (size_t)t*4;
      const float s0 = st[0], s1 = st[1], s2 = st[2], s3 = st[3];
      if (tid < EE)
        sSE[tid] = s0*p.Wemb[tid] + s1*p.Wemb[EE+tid]
                 + s2*p.Wemb[2*EE+tid] + s3*p.Wemb[3*EE+tid] + p.bemb[tid];
      float er0 = expf(ldA(ws + OFF_R0 + t));
      float v = (tid < NWG) ? ldA(ws + OFF_ES + tid) : 0.f;
      float invd = 1.f / (er0 + brs(v, s8, tid));
      {
        const int e4 = (tid & 31) * 4, qg = tid >> 5;
        f4 vv[4];
        ldA4x4(ws + OFF_EV + (size_t)(qg*4)*EE + e4, EE, vv);
        f4 acc = vv[0]+vv[1]+vv[2]+vv[3];
        *(f4*)(sBuf + (size_t)qg*EE + e4) = acc;
      }
      __syncthreads();
      if (tid < EE) {
        float s = 0.f;
        #pragma unroll
        for (int q = 0; q < 16; ++q) s += sBuf[(size_t)q*EE + tid];
        sMS[tid] = (er0*sSE[tid] + s) * invd;
      }
      __syncthreads();
      {
        f4 a = {0.f,0.f,0.f,0.f};
        const float* base = p.Ws + (size_t)(EE + eg4*32)*HSS + hq;
        for (int i = 0; i < 32; ++i)
          a += sMS[eg4*32 + i] * (*(const f4*)(base + (size_t)i*HSS));
        *(f4*)(sBuf + (size_t)eg4*HSS + hq) = a;
      }
      __syncthreads();
      {
        int j = tid;
        const float* cs = ws + OFF_CS;
        float sh0 = s0*cs[j] + s1*cs[HSS+j] + s2*cs[2*HSS+j] + s3*cs[3*HSS+j] + ws[OFF_CBS + j];
        float hv = sBuf[j] + sBuf[HSS+j] + sBuf[2*HSS+j] + sBuf[3*HSS+j] + sh0 + p.bs[j];
        sHv[j] = fmaxf(hv, 0.f);
      }
      __syncthreads();
      {
        int j = tid;
        float hv = sHv[j];
        float pa[6];
        #pragma unroll
        for (int aa = 0; aa < 5; ++aa) pa[aa] = hv * p.Wa[(size_t)j*5 + aa];
        pa[5] = hv * p.Wc[j];
        brsN<6>(pa, sR48, tid);
        if (tid == 0) {
          float l0=pa[0]+p.ba[0], l1=pa[1]+p.ba[1], l2=pa[2]+p.ba[2];
          float l3=pa[3]+p.ba[3], l4=pa[4]+p.ba[4];
          float mx = fmaxf(fmaxf(fmaxf(l0,l1),fmaxf(l2,l3)), l4);
          float e0=expf(l0-mx),e1=expf(l1-mx),e2=expf(l2-mx),e3=expf(l3-mx),e4v=expf(l4-mx);
          float is = 1.f/(e0+e1+e2+e3+e4v);
          float p0=e0*is,p1=e1*is,p2=e2*is,p3=e3*is,p4=e4v*is;
          p.out[(size_t)t*5+0]=p0; p.out[(size_t)t*5+1]=p1; p.out[(size_t)t*5+2]=p2;
          p.out[(size_t)t*5+3]=p3; p.out[(size_t)t*5+4]=p4;
          float val = pa[5] + p.bc[0];
          p.out[(size_t)BSZ*5 + t] = val;
          sSm[1]=p0; sSm[2]=p1; sSm[3]=p2; sSm[4]=p3; sSm[5]=p4; sSm[6]=val;
        }
        __syncthreads();
      }
      {
        const int cq = (tid & 63) * 4, eg8 = tid >> 6;
        f4 a = {0.f,0.f,0.f,0.f};
        const float* base = p.Wp1 + (size_t)(EE + eg8*16)*HPP + cq;
        for (int i = 0; i < 16; ++i)
          a += sMS[eg8*16 + i] * (*(const f4*)(base + (size_t)i*HPP));
        *(f4*)(sBuf + (size_t)eg8*HPP + cq) = a;
      }
      __syncthreads();
      if (tid < HPP) {
        int k = tid;
        const float* cp = ws + OFF_CP;
        float acc = s0*cp[k] + s1*cp[HPP+k] + s2*cp[2*HPP+k] + s3*cp[3*HPP+k]
                  + ws[OFF_CBP + k] + p.bp1[k];
        #pragma unroll
        for (int q = 0; q < 8; ++q) acc += sBuf[(size_t)q*HPP + k];
        #pragma unroll
        for (int aa = 0; aa < 5; ++aa) acc += sSm[1+aa] * p.Wp1[(size_t)(2*EE+aa)*HPP + k];
        acc += sSm[6] * p.Wp1[(size_t)(2*EE+5)*HPP + k];
        sP1[k] = fmaxf(acc, 0.f);
      }
      __syncthreads();
      {
        const int cq = (tid & 31) * 4, kg = tid >> 5;
        f4 a = {0.f,0.f,0.f,0.f};
        const float* base = p.Wp2 + (size_t)(kg*16)*EE + cq;
        for (int i = 0; i < 16; ++i)
          a += sP1[kg*16 + i] * (*(const f4*)(base + (size_t)i*EE));
        *(f4*)(sBuf + (size_t)kg*EE + cq) = a;
      }
      __syncthreads();
      if (tid < EE) {
        float s = 0.f;
        #pragma unroll
        for (int q = 0; q < 16; ++q) s += sBuf[(size_t)q*EE + tid];
        float m = s + p.bp2[tid];
        sMS[tid] = m;
        stA(ws + OFF_MS2 + tid, m);
      }
      __syncthreads();
      {
        f4 a = {0.f,0.f,0.f,0.f};
        const float* base = p.Ww1 + (size_t)(eg4*32)*HSS + hq;
        for (int i = 0; i < 32; ++i)
          a += sMS[eg4*32 + i] * (*(const f4*)(base + (size_t)i*HSS));
        *(f4*)(sBuf + (size_t)eg4*HSS + hq) = a;
      }
      __syncthreads();
      {
        int h = tid;
        stA(ws + OFF_HMS + h,
            fmaxf(sBuf[h] + sBuf[HSS+h] + sBuf[2*HSS+h] + sBuf[3*HSS+h] + p.bw1[h], 0.f));
      }
      drainSync();
      if (tid == 0) stAu(&bar[160], (unsigned)(t+1));
    }
  } else {
    // prologue: stageA(0) + stageC(0)
    __syncthreads();
    stageA();
    drainSync();
    if (tid == 0) stAu(&bar[g], 1u);
    stageC(ws + OFF_SW);
    drainSync();
    if (tid == 0) stAu(&bar[64+g], 1u);
    if (tid < NWG) {
      while (ldAu(&bar[64+tid]) < 1u) __builtin_amdgcn_s_sleep(1);
    }
    __syncthreads();

    for (int t = 0; t < BSZ-1; ++t) {
      dBulk(t);
      // wait leader(t)
      if (tid == 0) {
        while (ldAu(&bar[160]) < (unsigned)(t+1)) __builtin_amdgcn_s_sleep(1);
      }
      __syncthreads();
      dFinish(t);
      stageA();
      drainSync();
      if (tid == 0) stAu(&bar[g], (unsigned)(t+2));
      stageC(ws + OFF_SW + (size_t)((t+1)&1)*MM*MM);
      drainSync();
      if (tid == 0) stAu(&bar[64+g], (unsigned)(t+2));
      // worker-only C-barrier
      if (tid < NWG) {
        while (ldAu(&bar[64+tid]) < (unsigned)(t+2)) __builtin_amdgcn_s_sleep(1);
      }
      __syncthreads();
    }
  }
}

extern "C" void kernel_launch(void* const* d_in, const int* in_sizes, int n_in,
                              void* d_out, int out_size, void* d_ws, size_t ws_size,
                              hipStream_t stream) {
  hipMemsetAsync(d_ws, 0, 2048, stream);  // flags
  KParams kp;
  kp.state = (const float*)d_in[0];
  kp.mem0  = (const float*)d_in[1];
  kp.Wemb  = (const float*)d_in[2];
  kp.bemb  = (const float*)d_in[3];
  kp.Wr1   = (const float*)d_in[4];
  kp.br1   = (const float*)d_in[5];
  kp.Wr2   = (const float*)d_in[6];
  kp.br2   = (const float*)d_in[7];
  kp.Ww1   = (const float*)d_in[8];
  kp.bw1   = (const float*)d_in[9];
  kp.Ww2   = (const float*)d_in[10];
  kp.bw2   = (const float*)d_in[11];
  kp.Ws    = (const float*)d_in[12];
  kp.bs    = (const float*)d_in[13];
  kp.Wa    = (const float*)d_in[14];
  kp.ba    = (const float*)d_in[15];
  kp.Wc    = (const float*)d_in[16];
  kp.bc    = (const float*)d_in[17];
  kp.Wp1   = (const float*)d_in[18];
  kp.bp1   = (const float*)d_in[19];
  kp.Wp2   = (const float*)d_in[20];
  kp.bp2   = (const float*)d_in[21];
  kp.out   = (float*)d_out;
  kp.ws    = (float*)d_ws;
  toyac_kernel<<<dim3(NWGT), dim3(TPB), 0, stream>>>(kp);
}

// Round 7
// 54944.183 us; speedup vs baseline: 32.2465x; 1.1539x over previous
//
#include <hip/hip_runtime.h>
#include <math.h>

#define BSZ 2048   // batch steps
#define MM  256    // memory slots
#define EE  128    // embedding dim
#define HSS 512    // summarizer hidden
#define HPP 256    // processor hidden
#define NOWN 64    // owner blocks (4 memory rows each)
#define NBLK 129   // owners + helpers + leader
#define LEADER 128
#define TPB 512
#define ROWS 4

typedef float f4 __attribute__((ext_vector_type(4)));

// flags (uints, memset 0): bar[0..63]=rowFlag, [64..127]=flagA, [128..191]=scFlag,
// [192..255]=bulkFlag, [320]=msFlag
#define OFF_PE   512
#define OFF_R0   (OFF_PE + MM*EE)
#define OFF_W0   (OFF_R0 + BSZ)
#define OFF_MP   (OFF_W0 + BSZ*MM)        // memPE double buffer: 2*MM*EE
#define OFF_SW   (OFF_MP + 2*MM*EE)       // writer scores [buf][row][col]: 2*MM*MM
#define OFF_EV   (OFF_SW + 2*MM*MM)       // per-owner exp-weighted partials: NOWN*EE
#define OFF_ES   (OFF_EV + NOWN*EE)       // per-owner exp sums: NOWN
#define OFF_MS2  (OFF_ES + NOWN)          // ms2: EE
#define OFF_CS   (OFF_MS2 + EE)           // Wemb@Ws[0:128,:]: 4*HSS (leader-local)
#define OFF_CBS  (OFF_CS + 4*HSS)
#define OFF_CP   (OFF_CBS + HSS)          // Wemb@Wp1[0:128,:]: 4*HPP
#define OFF_CBP  (OFF_CP + 4*HPP)
#define OFF_BD   (OFF_CBP + HPP)          // helper denom partials: NOWN*ROWS
#define OFF_BP   (OFF_BD + NOWN*ROWS)     // helper weighted partials: NOWN*ROWS*EE

struct KParams {
  const float *state, *mem0, *Wemb, *bemb, *Wr1, *br1, *Wr2, *br2;
  const float *Ww1, *bw1, *Ww2, *bw2, *Ws, *bs, *Wa, *ba, *Wc, *bc;
  const float *Wp1, *bp1, *Wp2, *bp2;
  float *out;
  float *ws;
};

// ---- relaxed agent-scope ops (coherent across XCDs, no cache maintenance) ----
__device__ __forceinline__ float ldA(const float* p) {
  return __hip_atomic_load(p, __ATOMIC_RELAXED, __HIP_MEMORY_SCOPE_AGENT);
}
__device__ __forceinline__ void stA(float* p, float v) {
  __hip_atomic_store(p, v, __ATOMIC_RELAXED, __HIP_MEMORY_SCOPE_AGENT);
}
__device__ __forceinline__ unsigned ldAu(const unsigned* p) {
  return __hip_atomic_load(p, __ATOMIC_RELAXED, __HIP_MEMORY_SCOPE_AGENT);
}
__device__ __forceinline__ void stAu(unsigned* p, unsigned v) {
  __hip_atomic_store(p, v, __ATOMIC_RELAXED, __HIP_MEMORY_SCOPE_AGENT);
}

// ---- batched L2-bypass vector loads ----
__device__ __forceinline__ void ldA4x8(const float* p, int strideF, f4* v) {
  const float *p1=p+strideF, *p2=p+2*strideF, *p3=p+3*strideF,
              *p4=p+4*strideF, *p5=p+5*strideF, *p6=p+6*strideF, *p7=p+7*strideF;
  asm volatile(
    "global_load_dwordx4 %0, %8, off sc0 sc1\n\t"
    "global_load_dwordx4 %1, %9, off sc0 sc1\n\t"
    "global_load_dwordx4 %2, %10, off sc0 sc1\n\t"
    "global_load_dwordx4 %3, %11, off sc0 sc1\n\t"
    "global_load_dwordx4 %4, %12, off sc0 sc1\n\t"
    "global_load_dwordx4 %5, %13, off sc0 sc1\n\t"
    "global_load_dwordx4 %6, %14, off sc0 sc1\n\t"
    "global_load_dwordx4 %7, %15, off sc0 sc1\n\t"
    "s_waitcnt vmcnt(0)"
    : "=&v"(v[0]), "=&v"(v[1]), "=&v"(v[2]), "=&v"(v[3]),
      "=&v"(v[4]), "=&v"(v[5]), "=&v"(v[6]), "=&v"(v[7])
    : "v"(p), "v"(p1), "v"(p2), "v"(p3), "v"(p4), "v"(p5), "v"(p6), "v"(p7)
    : "memory");
}
__device__ __forceinline__ void ldA4x4(const float* p, int strideF, f4* v) {
  const float *p1=p+strideF, *p2=p+2*strideF, *p3=p+3*strideF;
  asm volatile(
    "global_load_dwordx4 %0, %4, off sc0 sc1\n\t"
    "global_load_dwordx4 %1, %5, off sc0 sc1\n\t"
    "global_load_dwordx4 %2, %6, off sc0 sc1\n\t"
    "global_load_dwordx4 %3, %7, off sc0 sc1\n\t"
    "s_waitcnt vmcnt(0)"
    : "=&v"(v[0]), "=&v"(v[1]), "=&v"(v[2]), "=&v"(v[3])
    : "v"(p), "v"(p1), "v"(p2), "v"(p3)
    : "memory");
}
__device__ __forceinline__ f4 ldA4(const float* p) {
  f4 r;
  asm volatile("global_load_dwordx4 %0, %1, off sc0 sc1\n\ts_waitcnt vmcnt(0)"
    : "=&v"(r) : "v"(p) : "memory");
  return r;
}

__device__ __forceinline__ void drainSync() {
  asm volatile("s_waitcnt vmcnt(0)" ::: "memory");
  __syncthreads();
}

__device__ __forceinline__ float brs(float v, float* s8, int tid) {
  for (int o = 32; o > 0; o >>= 1) v += __shfl_down(v, o, 64);
  __syncthreads();
  if ((tid & 63) == 0) s8[tid >> 6] = v;
  __syncthreads();
  float r = s8[0]+s8[1]+s8[2]+s8[3]+s8[4]+s8[5]+s8[6]+s8[7];
  __syncthreads();
  return r;
}

template<int N>
__device__ __forceinline__ void brsN(float* v, float* sred, int tid) {
  #pragma unroll
  for (int k = 0; k < N; ++k)
    for (int o = 32; o > 0; o >>= 1) v[k] += __shfl_down(v[k], o, 64);
  __syncthreads();
  if ((tid & 63) == 0) {
    const int w = tid >> 6;
    #pragma unroll
    for (int k = 0; k < N; ++k) sred[k*8 + w] = v[k];
  }
  __syncthreads();
  #pragma unroll
  for (int k = 0; k < N; ++k) {
    float s = sred[k*8 + 0];
    #pragma unroll
    for (int w = 1; w < 8; ++w) s += sred[k*8 + w];
    v[k] = s;
  }
  __syncthreads();
}

__global__ __launch_bounds__(TPB)
void toyac_kernel(KParams p) {
  const int g = blockIdx.x;
  const int tid = threadIdx.x;
  float* ws = p.ws;
  unsigned* bar = (unsigned*)p.ws;
  const int og = (g >= NOWN && g < LEADER) ? (g - NOWN) : g;  // owner index for helpers
  const int c0 = ROWS * ((g < NOWN) ? g : og);

  __shared__ float sX[ROWS][EE];
  __shared__ float sBuf[8192];
  __shared__ float sH4[ROWS][HSS];
  __shared__ float sHms[HSS];
  __shared__ float sEv[ROWS][MM];
  __shared__ float sRed[16];
  __shared__ float s8[8];
  __shared__ float sR48[48];
  __shared__ float sMS[EE];
  __shared__ float sMS2[EE];
  __shared__ float sSE[EE];
  __shared__ float sP1[HPP];
  __shared__ float sHv[HSS];
  __shared__ float sD[ROWS];
  __shared__ float sSm[32];

  const int hq = (tid & 127) * 4;
  const int eg4 = tid >> 7;

  // ================= P0a =================
  if (g < NOWN) {
    const int e = tid & 127, r = tid >> 7, c = c0 + r;
    double dv = exp(-(double)(2*(e>>1)) * log(10000.0) / 128.0);
    double arg = (double)c * dv;
    float pev = ((e & 1) == 0) ? (float)sin(arg) : (float)cos(arg);
    ws[OFF_PE + (size_t)c*EE + e] = pev;
    float m0v = p.mem0[(size_t)c*EE + e] + pev;
    stA(ws + OFF_MP + (size_t)c*EE + e, m0v);
    sX[r][e] = m0v;
  } else if (g == LEADER) {
    for (int jj = tid; jj < HSS; jj += TPB) {
      float a0=0.f,a1=0.f,a2=0.f,a3=0.f,cb=0.f;
      for (int e = 0; e < EE; ++e) {
        float wv = p.Ws[(size_t)e*HSS + jj];
        a0 += p.Wemb[e]*wv; a1 += p.Wemb[EE+e]*wv;
        a2 += p.Wemb[2*EE+e]*wv; a3 += p.Wemb[3*EE+e]*wv;
        cb += p.bemb[e]*wv;
      }
      ws[OFF_CS + jj] = a0; ws[OFF_CS + HSS + jj] = a1;
      ws[OFF_CS + 2*HSS + jj] = a2; ws[OFF_CS + 3*HSS + jj] = a3;
      ws[OFF_CBS + jj] = cb;
    }
    if (tid < HPP) {
      int k = tid;
      float a0=0.f,a1=0.f,a2=0.f,a3=0.f,cb=0.f;
      for (int e = 0; e < EE; ++e) {
        float wv = p.Wp1[(size_t)e*HPP + k];
        a0 += p.Wemb[e]*wv; a1 += p.Wemb[EE+e]*wv;
        a2 += p.Wemb[2*EE+e]*wv; a3 += p.Wemb[3*EE+e]*wv;
        cb += p.bemb[e]*wv;
      }
      ws[OFF_CP + k] = a0; ws[OFF_CP + HPP + k] = a1;
      ws[OFF_CP + 2*HPP + k] = a2; ws[OFF_CP + 3*HPP + k] = a3;
      ws[OFF_CBP + k] = cb;
    }
  }

  // ================= P0b: per-step R0, W0 (striped over all 129 blocks) =============
  for (int t = g; t < BSZ; t += NBLK) {
    __syncthreads();
    if (tid < EE) {
      const float* st = p.state + (size_t)t*4;
      sSE[tid] = st[0]*p.Wemb[tid] + st[1]*p.Wemb[EE+tid]
               + st[2]*p.Wemb[2*EE+tid] + st[3]*p.Wemb[3*EE+tid] + p.bemb[tid];
    }
    __syncthreads();
    { // reader score r0
      f4 a = {0.f,0.f,0.f,0.f};
      const float* base = p.Wr1 + (size_t)(eg4*32)*HSS + hq;
      for (int i = 0; i < 32; ++i)
        a += sSE[eg4*32 + i] * (*(const f4*)(base + (size_t)i*HSS));
      *(f4*)(sBuf + (size_t)eg4*HSS + hq) = a;
      __syncthreads();
      int h = tid;
      float hid = sBuf[h] + sBuf[HSS+h] + sBuf[2*HSS+h] + sBuf[3*HSS+h] + p.br1[h];
      float v = fmaxf(hid, 0.f) * p.Wr2[h];
      float sc = brs(v, s8, tid);
      if (tid == 0) stA(ws + OFF_R0 + t, sc + p.br2[0]);
      __syncthreads();
    }
    { // writer row0
      f4 a = {0.f,0.f,0.f,0.f};
      const float* base = p.Ww1 + (size_t)(eg4*32)*HSS + hq;
      for (int i = 0; i < 32; ++i)
        a += sSE[eg4*32 + i] * (*(const f4*)(base + (size_t)i*HSS));
      *(f4*)(sBuf + (size_t)eg4*HSS + hq) = a;
      __syncthreads();
      int h = tid;
      sHv[h] = fmaxf(sBuf[h] + sBuf[HSS+h] + sBuf[2*HSS+h] + sBuf[3*HSS+h] + p.bw1[h], 0.f);
      __syncthreads();
      const int cq = (tid & 63) * 4, hg = tid >> 6;
      f4 q = {0.f,0.f,0.f,0.f};
      const float* b2 = p.Ww2 + (size_t)(hg*64)*MM + cq;
      for (int i = 0; i < 64; ++i)
        q += sHv[hg*64 + i] * (*(const f4*)(b2 + (size_t)i*MM));
      *(f4*)(sBuf + (size_t)hg*MM + cq) = q;
      __syncthreads();
      if (tid < MM) {
        float s = 0.f;
        #pragma unroll
        for (int k = 0; k < 8; ++k) s += sBuf[(size_t)k*MM + tid];
        stA(ws + OFF_W0 + (size_t)t*MM + tid, s + p.bw2[tid]);
      }
      __syncthreads();
    }
  }

  // ================= role lambdas =================
  auto stageA = [&]() {   // owner: reader scores -> EV/ES
    {
      f4 a0={0.f,0.f,0.f,0.f},a1=a0,a2=a0,a3=a0;
      const float* base = p.Wr1 + (size_t)(eg4*32)*HSS + hq;
      for (int i = 0; i < 32; ++i) {
        f4 w = *(const f4*)(base + (size_t)i*HSS);
        int e = eg4*32 + i;
        a0 += sX[0][e]*w; a1 += sX[1][e]*w; a2 += sX[2][e]*w; a3 += sX[3][e]*w;
      }
      *(f4*)(sBuf + ((size_t)eg4*ROWS + 0)*HSS + hq) = a0;
      *(f4*)(sBuf + ((size_t)eg4*ROWS + 1)*HSS + hq) = a1;
      *(f4*)(sBuf + ((size_t)eg4*ROWS + 2)*HSS + hq) = a2;
      *(f4*)(sBuf + ((size_t)eg4*ROWS + 3)*HSS + hq) = a3;
    }
    __syncthreads();
    float es[ROWS];
    {
      int h = tid;
      float b = p.br1[h], wr = p.Wr2[h];
      float sc[ROWS];
      #pragma unroll
      for (int r = 0; r < ROWS; ++r) {
        float hid = sBuf[(0*ROWS+r)*HSS+h] + sBuf[(1*ROWS+r)*HSS+h]
                  + sBuf[(2*ROWS+r)*HSS+h] + sBuf[(3*ROWS+r)*HSS+h] + b;
        sc[r] = fmaxf(hid, 0.f) * wr;
      }
      brsN<ROWS>(sc, sR48, tid);
      #pragma unroll
      for (int r = 0; r < ROWS; ++r) es[r] = expf(sc[r] + p.br2[0]);
    }
    if (tid < EE) {
      float v = es[0]*sX[0][tid] + es[1]*sX[1][tid] + es[2]*sX[2][tid] + es[3]*sX[3][tid];
      stA(ws + OFF_EV + (size_t)g*EE + tid, v);
    }
    if (tid == 0) stA(ws + OFF_ES + g, es[0]+es[1]+es[2]+es[3]);
  };

  auto stageC = [&](float* swdst) {  // helper: writer score rows for own 4 rows
    {
      f4 a0={0.f,0.f,0.f,0.f},a1=a0,a2=a0,a3=a0;
      const float* base = p.Ww1 + (size_t)(eg4*32)*HSS + hq;
      for (int i = 0; i < 32; ++i) {
        f4 w = *(const f4*)(base + (size_t)i*HSS);
        int e = eg4*32 + i;
        a0 += sX[0][e]*w; a1 += sX[1][e]*w; a2 += sX[2][e]*w; a3 += sX[3][e]*w;
      }
      *(f4*)(sBuf + ((size_t)eg4*ROWS + 0)*HSS + hq) = a0;
      *(f4*)(sBuf + ((size_t)eg4*ROWS + 1)*HSS + hq) = a1;
      *(f4*)(sBuf + ((size_t)eg4*ROWS + 2)*HSS + hq) = a2;
      *(f4*)(sBuf + ((size_t)eg4*ROWS + 3)*HSS + hq) = a3;
    }
    __syncthreads();
    {
      int h = tid;
      float b = p.bw1[h];
      #pragma unroll
      for (int r = 0; r < ROWS; ++r)
        sH4[r][h] = fmaxf(sBuf[(0*ROWS+r)*HSS+h] + sBuf[(1*ROWS+r)*HSS+h]
                        + sBuf[(2*ROWS+r)*HSS+h] + sBuf[(3*ROWS+r)*HSS+h] + b, 0.f);
    }
    __syncthreads();
    {
      const int cq = (tid & 63) * 4, hg = tid >> 6;
      f4 q0={0.f,0.f,0.f,0.f},q1=q0,q2=q0,q3=q0;
      const float* b2 = p.Ww2 + (size_t)(hg*64)*MM + cq;
      for (int i = 0; i < 64; ++i) {
        f4 w = *(const f4*)(b2 + (size_t)i*MM);
        int h = hg*64 + i;
        q0 += sH4[0][h]*w; q1 += sH4[1][h]*w; q2 += sH4[2][h]*w; q3 += sH4[3][h]*w;
      }
      *(f4*)(sBuf + ((size_t)hg*ROWS + 0)*MM + cq) = q0;
      *(f4*)(sBuf + ((size_t)hg*ROWS + 1)*MM + cq) = q1;
      *(f4*)(sBuf + ((size_t)hg*ROWS + 2)*MM + cq) = q2;
      *(f4*)(sBuf + ((size_t)hg*ROWS + 3)*MM + cq) = q3;
    }
    __syncthreads();
    {
      const int col = tid & 255, rp = tid >> 8;
      #pragma unroll
      for (int rr = 0; rr < 2; ++rr) {
        int r = rp*2 + rr;
        float s = 0.f;
        #pragma unroll
        for (int k = 0; k < 8; ++k) s += sBuf[((size_t)k*ROWS + r)*MM + col];
        stA(swdst + (size_t)(c0 + r)*MM + col, s + p.bw2[col]);
      }
    }
  };

  auto dBulkH = [&](int t) {  // helper: exp + denoms + weighted sums -> global partials
    float* swc = ws + OFF_SW + (size_t)(t&1)*MM*MM;
    float* mpc = ws + OFF_MP + (size_t)(t&1)*MM*EE;
    float ex[ROWS] = {0.f,0.f,0.f,0.f};
    if (tid < MM) {
      f4 s = ldA4(swc + (size_t)tid*MM + c0);
      #pragma unroll
      for (int r = 0; r < ROWS; ++r) { ex[r] = expf(s[r]); sEv[r][tid] = ex[r]; }
    }
    brsN<ROWS>(ex, sR48, tid);
    if (tid == 0) {
      stA(ws + OFF_BD + og*ROWS + 0, ex[0]);
      stA(ws + OFF_BD + og*ROWS + 1, ex[1]);
      stA(ws + OFF_BD + og*ROWS + 2, ex[2]);
      stA(ws + OFF_BD + og*ROWS + 3, ex[3]);
    }
    {
      const int e4 = (tid & 31) * 4, rg = tid >> 5;
      f4 a0={0.f,0.f,0.f,0.f},a1=a0,a2=a0,a3=a0;
      const float* base = mpc + (size_t)(rg*16)*EE + e4;
      f4 vv[8];
      ldA4x8(base, EE, vv);
      #pragma unroll
      for (int i = 0; i < 8; ++i) {
        int r0 = rg*16 + i;
        a0 += sEv[0][r0]*vv[i]; a1 += sEv[1][r0]*vv[i];
        a2 += sEv[2][r0]*vv[i]; a3 += sEv[3][r0]*vv[i];
      }
      ldA4x8(base + 8*EE, EE, vv);
      #pragma unroll
      for (int i = 0; i < 8; ++i) {
        int r0 = rg*16 + 8 + i;
        a0 += sEv[0][r0]*vv[i]; a1 += sEv[1][r0]*vv[i];
        a2 += sEv[2][r0]*vv[i]; a3 += sEv[3][r0]*vv[i];
      }
      *(f4*)(sBuf + ((size_t)0*16 + rg)*EE + e4) = a0;
      *(f4*)(sBuf + ((size_t)1*16 + rg)*EE + e4) = a1;
      *(f4*)(sBuf + ((size_t)2*16 + rg)*EE + e4) = a2;
      *(f4*)(sBuf + ((size_t)3*16 + rg)*EE + e4) = a3;
    }
    __syncthreads();
    {
      const int e = tid & 127, r = tid >> 7;
      float s = 0.f;
      #pragma unroll
      for (int q = 0; q < 16; ++q) s += sBuf[((size_t)r*16 + q)*EE + e];
      stA(ws + OFF_BP + ((size_t)og*ROWS + r)*EE + e, s);
    }
  };

  // ================= main =================
  if (g == LEADER) {
    for (int t = 0; t < BSZ; ++t) {
      if (tid < NOWN) {
        while (ldAu(&bar[64+tid]) < (unsigned)(t+1)) __builtin_amdgcn_s_sleep(1);
      }
      __syncthreads();
      const float* st = p.state + (size_t)t*4;
      const float s0 = st[0], s1 = st[1], s2 = st[2], s3 = st[3];
      if (tid < EE)
        sSE[tid] = s0*p.Wemb[tid] + s1*p.Wemb[EE+tid]
                 + s2*p.Wemb[2*EE+tid] + s3*p.Wemb[3*EE+tid] + p.bemb[tid];
      float er0 = expf(ldA(ws + OFF_R0 + t));
      float v = (tid < NOWN) ? ldA(ws + OFF_ES + tid) : 0.f;
      float invd = 1.f / (er0 + brs(v, s8, tid));
      {
        const int e4 = (tid & 31) * 4, qg = tid >> 5;
        f4 vv[4];
        ldA4x4(ws + OFF_EV + (size_t)(qg*4)*EE + e4, EE, vv);
        f4 acc = vv[0]+vv[1]+vv[2]+vv[3];
        *(f4*)(sBuf + (size_t)qg*EE + e4) = acc;
      }
      __syncthreads();
      if (tid < EE) {
        float s = 0.f;
        #pragma unroll
        for (int q = 0; q < 16; ++q) s += sBuf[(size_t)q*EE + tid];
        sMS[tid] = (er0*sSE[tid] + s) * invd;
      }
      __syncthreads();
      {
        f4 a = {0.f,0.f,0.f,0.f};
        const float* base = p.Ws + (size_t)(EE + eg4*32)*HSS + hq;
        for (int i = 0; i < 32; ++i)
          a += sMS[eg4*32 + i] * (*(const f4*)(base + (size_t)i*HSS));
        *(f4*)(sBuf + (size_t)eg4*HSS + hq) = a;
      }
      __syncthreads();
      {
        int j = tid;
        const float* cs = ws + OFF_CS;
        float sh0 = s0*cs[j] + s1*cs[HSS+j] + s2*cs[2*HSS+j] + s3*cs[3*HSS+j] + ws[OFF_CBS + j];
        float hv = sBuf[j] + sBuf[HSS+j] + sBuf[2*HSS+j] + sBuf[3*HSS+j] + sh0 + p.bs[j];
        sHv[j] = fmaxf(hv, 0.f);
      }
      __syncthreads();
      {
        int j = tid;
        float hv = sHv[j];
        float pa[6];
        #pragma unroll
        for (int aa = 0; aa < 5; ++aa) pa[aa] = hv * p.Wa[(size_t)j*5 + aa];
        pa[5] = hv * p.Wc[j];
        brsN<6>(pa, sR48, tid);
        if (tid == 0) {
          float l0=pa[0]+p.ba[0], l1=pa[1]+p.ba[1], l2=pa[2]+p.ba[2];
          float l3=pa[3]+p.ba[3], l4=pa[4]+p.ba[4];
          float mx = fmaxf(fmaxf(fmaxf(l0,l1),fmaxf(l2,l3)), l4);
          float e0=expf(l0-mx),e1=expf(l1-mx),e2=expf(l2-mx),e3=expf(l3-mx),e4v=expf(l4-mx);
          float is = 1.f/(e0+e1+e2+e3+e4v);
          float p0=e0*is,p1=e1*is,p2=e2*is,p3=e3*is,p4=e4v*is;
          p.out[(size_t)t*5+0]=p0; p.out[(size_t)t*5+1]=p1; p.out[(size_t)t*5+2]=p2;
          p.out[(size_t)t*5+3]=p3; p.out[(size_t)t*5+4]=p4;
          float val = pa[5] + p.bc[0];
          p.out[(size_t)BSZ*5 + t] = val;
          sSm[1]=p0; sSm[2]=p1; sSm[3]=p2; sSm[4]=p3; sSm[5]=p4; sSm[6]=val;
        }
        __syncthreads();
      }
      {
        const int cq = (tid & 63) * 4, eg8 = tid >> 6;
        f4 a = {0.f,0.f,0.f,0.f};
        const float* base = p.Wp1 + (size_t)(EE + eg8*16)*HPP + cq;
        for (int i = 0; i < 16; ++i)
          a += sMS[eg8*16 + i] * (*(const f4*)(base + (size_t)i*HPP));
        *(f4*)(sBuf + (size_t)eg8*HPP + cq) = a;
      }
      __syncthreads();
      if (tid < HPP) {
        int k = tid;
        const float* cp = ws + OFF_CP;
        float acc = s0*cp[k] + s1*cp[HPP+k] + s2*cp[2*HPP+k] + s3*cp[3*HPP+k]
                  + ws[OFF_CBP + k] + p.bp1[k];
        #pragma unroll
        for (int q = 0; q < 8; ++q) acc += sBuf[(size_t)q*HPP + k];
        #pragma unroll
        for (int aa = 0; aa < 5; ++aa) acc += sSm[1+aa] * p.Wp1[(size_t)(2*EE+aa)*HPP + k];
        acc += sSm[6] * p.Wp1[(size_t)(2*EE+5)*HPP + k];
        sP1[k] = fmaxf(acc, 0.f);
      }
      __syncthreads();
      {
        const int cq = (tid & 31) * 4, kg = tid >> 5;
        f4 a = {0.f,0.f,0.f,0.f};
        const float* base = p.Wp2 + (size_t)(kg*16)*EE + cq;
        for (int i = 0; i < 16; ++i)
          a += sP1[kg*16 + i] * (*(const f4*)(base + (size_t)i*EE));
        *(f4*)(sBuf + (size_t)kg*EE + cq) = a;
      }
      __syncthreads();
      if (tid < EE) {
        float s = 0.f;
        #pragma unroll
        for (int q = 0; q < 16; ++q) s += sBuf[(size_t)q*EE + tid];
        stA(ws + OFF_MS2 + tid, s + p.bp2[tid]);
      }
      drainSync();
      if (tid == 0) stAu(&bar[320], (unsigned)(t+1));
    }
  } else if (g < NOWN) {
    // -------- OWNER --------
    const f4 wcol = *(const f4*)(p.Ww2 + (size_t)tid*MM + c0);  // step-invariant
    drainSync();
    if (tid == 0) stAu(&bar[g], 1u);       // rows(0) ready
    stageA();
    drainSync();
    if (tid == 0) stAu(&bar[64+g], 1u);    // stageA(0) done

    for (int t = 0; t < BSZ-1; ++t) {
      // flag-independent precompute
      if (tid < EE) {
        const float* st = p.state + (size_t)t*4;
        sSE[tid] = st[0]*p.Wemb[tid] + st[1]*p.Wemb[EE+tid]
                 + st[2]*p.Wemb[2*EE+tid] + st[3]*p.Wemb[3*EE+tid] + p.bemb[tid];
      }
      if (tid == 0) {
        f4 w0 = ldA4(ws + OFF_W0 + (size_t)t*MM + c0);
        #pragma unroll
        for (int r = 0; r < ROWS; ++r) sSm[8+r] = expf(w0[r]);
      }
      // wait leader ms2(t)
      if (tid == 0) {
        while (ldAu(&bar[320]) < (unsigned)(t+1)) __builtin_amdgcn_s_sleep(1);
      }
      __syncthreads();
      if (tid < EE) sMS2[tid] = ldA(ws + OFF_MS2 + tid);
      __syncthreads();
      // hms = relu(ms2 @ Ww1 + bw1)
      {
        f4 a = {0.f,0.f,0.f,0.f};
        const float* base = p.Ww1 + (size_t)(eg4*32)*HSS + hq;
        for (int i = 0; i < 32; ++i)
          a += sMS2[eg4*32 + i] * (*(const f4*)(base + (size_t)i*HSS));
        *(f4*)(sBuf + (size_t)eg4*HSS + hq) = a;
      }
      __syncthreads();
      sHms[tid] = fmaxf(sBuf[tid] + sBuf[HSS+tid] + sBuf[2*HSS+tid] + sBuf[3*HSS+tid]
                        + p.bw1[tid], 0.f);
      __syncthreads();
      // sw1 for own 4 cols
      float swv[ROWS];
      {
        float hm = sHms[tid];
        swv[0] = hm*wcol.x; swv[1] = hm*wcol.y; swv[2] = hm*wcol.z; swv[3] = hm*wcol.w;
        brsN<ROWS>(swv, sR48, tid);
      }
      // wait helper bulk(t)
      if (tid == 0) {
        while (ldAu(&bar[192+g]) < (unsigned)(t+1)) __builtin_amdgcn_s_sleep(1);
      }
      __syncthreads();
      if (tid == 0) {
        f4 d = ldA4(ws + OFF_BD + g*ROWS);
        sD[0]=d.x; sD[1]=d.y; sD[2]=d.z; sD[3]=d.w;
      }
      __syncthreads();
      // dFinish
      {
        const int e = tid & 127, r = tid >> 7;
        float bp = ldA(ws + OFF_BP + ((size_t)g*ROWS + r)*EE + e);
        float ew1 = expf(swv[r] + p.bw2[c0+r]);
        float ew0 = sSm[8+r];
        float inv = 1.f / (sD[r] + ew0 + ew1);
        float x = (bp + ew0*sSE[e] + ew1*sMS2[e]) * inv;
        // per-row min/max via wave shuffles (row = 2 waves)
        float mn = x, mx = x;
        #pragma unroll
        for (int o = 1; o < 64; o <<= 1) {
          mn = fminf(mn, __shfl_xor(mn, o, 64));
          mx = fmaxf(mx, __shfl_xor(mx, o, 64));
        }
        if ((tid & 63) == 0) { sRed[(tid>>6)*2] = mn; sRed[(tid>>6)*2+1] = mx; }
        __syncthreads();
        mn = fminf(sRed[4*r], sRed[4*r+2]);
        mx = fmaxf(sRed[4*r+1], sRed[4*r+3]);
        float xr = (x - mn) / (mx - mn) + ws[OFF_PE + (size_t)(c0+r)*EE + e];
        float* mpn = ws + OFF_MP + (size_t)((t+1)&1)*MM*EE;
        stA(mpn + (size_t)(c0+r)*EE + e, xr);
        sX[r][e] = xr;
      }
      drainSync();
      if (tid == 0) stAu(&bar[g], (unsigned)(t+2));   // rows(t+1) ready
      stageA();
      drainSync();
      if (tid == 0) stAu(&bar[64+g], (unsigned)(t+2)); // stageA(t+1) done
    }
  } else {
    // -------- HELPER (og = g-64) --------
    float* mpB[2] = { ws + OFF_MP, ws + OFF_MP + (size_t)MM*EE };
    for (int t = 0; t < BSZ-1; ++t) {
      if (tid == 0) {
        while (ldAu(&bar[og]) < (unsigned)(t+1)) __builtin_amdgcn_s_sleep(1);
      }
      __syncthreads();
      {
        const int e = tid & 127, r = tid >> 7;
        sX[r][e] = ldA(mpB[t&1] + (size_t)(c0+r)*EE + e);
      }
      __syncthreads();
      stageC(ws + OFF_SW + (size_t)(t&1)*MM*MM);
      drainSync();
      if (tid == 0) stAu(&bar[128+og], (unsigned)(t+1));
      // wait all scores + all rows for step t
      if (tid < 64) {
        while (ldAu(&bar[128+tid]) < (unsigned)(t+1)) __builtin_amdgcn_s_sleep(1);
      } else if (tid < 128) {
        while (ldAu(&bar[tid-64]) < (unsigned)(t+1)) __builtin_amdgcn_s_sleep(1);
      }
      __syncthreads();
      dBulkH(t);
      drainSync();
      if (tid == 0) stAu(&bar[192+og], (unsigned)(t+1));
    }
  }
}

extern "C" void kernel_launch(void* const* d_in, const int* in_sizes, int n_in,
                              void* d_out, int out_size, void* d_ws, size_t ws_size,
                              hipStream_t stream) {
  hipMemsetAsync(d_ws, 0, 2048, stream);  // flags
  KParams kp;
  kp.state = (const float*)d_in[0];
  kp.mem0  = (const float*)d_in[1];
  kp.Wemb  = (const float*)d_in[2];
  kp.bemb  = (const float*)d_in[3];
  kp.Wr1   = (const float*)d_in[4];
  kp.br1   = (const float*)d_in[5];
  kp.Wr2   = (const float*)d_in[6];
  kp.br2   = (const float*)d_in[7];
  kp.Ww1   = (const float*)d_in[8];
  kp.bw1   = (const float*)d_in[9];
  kp.Ww2   = (const float*)d_in[10];
  kp.bw2   = (const float*)d_in[11];
  kp.Ws    = (const float*)d_in[12];
  kp.bs    = (const float*)d_in[13];
  kp.Wa    = (const float*)d_in[14];
  kp.ba    = (const float*)d_in[15];
  kp.Wc    = (const float*)d_in[16];
  kp.bc    = (const float*)d_in[17];
  kp.Wp1   = (const float*)d_in[18];
  kp.bp1   = (const float*)d_in[19];
  kp.Wp2   = (const float*)d_in[20];
  kp.bp2   = (const float*)d_in[21];
  kp.out   = (float*)d_out;
  kp.ws    = (float*)d_ws;
  toyac_kernel<<<dim3(NBLK), dim3(TPB), 0, stream>>>(kp);
}